// Round 16
// baseline (427.374 us; speedup 1.0000x reference)
//
#include <hip/hip_runtime.h>
#include <hip/hip_bf16.h>
#include <math.h>

#define DEV_INLINE __device__ __forceinline__

typedef float f32x4 __attribute__((ext_vector_type(4)));
typedef short bf16x8 __attribute__((ext_vector_type(8)));
typedef short s16x4 __attribute__((ext_vector_type(4)));

constexpr int B_    = 4;
constexpr int QLEN  = 512;
constexpr int KLEN  = 1024;
constexpr int DIM   = 512;
constexpr int H_MA  = 4;
constexpr int H_CA  = 2;
constexpr int CHUNK = 4;
constexpr float EPS = 1e-6f;
constexpr float INV_SCALE = 1.0f / 22.62741699796952f;  // 1/sqrt(512)

// ---------------------------------------------------------------------------
// fp32 -> bf16 hi/lo split (RNE both halves; a ~= hi + lo)
// ---------------------------------------------------------------------------

DEV_INLINE unsigned short f2bf(float x) {
    unsigned int u = __float_as_uint(x);
    unsigned int r = u + 0x7FFFu + ((u >> 16) & 1u);
    return (unsigned short)(r >> 16);
}

DEV_INLINE void split2(float x, short& h, short& l) {
    const unsigned short hb = f2bf(x);
    const float hf = __uint_as_float(((unsigned int)hb) << 16);
    h = (short)hb;
    l = (short)f2bf(x - hf);
}

DEV_INLINE float bf2f(short s) {
    return __uint_as_float(((unsigned int)(unsigned short)s) << 16);
}

__global__ __launch_bounds__(256) void rowsplit_kernel(
    const float* __restrict__ X, short* __restrict__ Xh,
    short* __restrict__ Xl, int n4)
{
    const int i = blockIdx.x * 256 + threadIdx.x;
    if (i >= n4) return;
    const f32x4 v = *(const f32x4*)(X + (size_t)i * 4);
    s16x4 h, l;
#pragma unroll
    for (int j = 0; j < 4; ++j) {
        short hh, ll;
        split2(v[j], hh, ll);
        h[j] = hh; l[j] = ll;
    }
    *(s16x4*)(Xh + (size_t)i * 4) = h;
    *(s16x4*)(Xl + (size_t)i * 4) = l;
}

// W[512,512] fp32 -> WTh, WTl [N,K]=[512,512] bf16 (transposed), ld 512
__global__ __launch_bounds__(256) void transsplit_kernel(
    const float* __restrict__ W, short* __restrict__ WTh,
    short* __restrict__ WTl)
{
    __shared__ __align__(16) short Th[64][72];
    __shared__ __align__(16) short Tl[64][72];
    const int t = threadIdx.x;
    const int k0 = blockIdx.x * 64;
    const int n0 = blockIdx.y * 64;
#pragma unroll
    for (int i = 0; i < 4; ++i) {
        const int c  = t + 256 * i;
        const int kr = c >> 4;
        const int nc = c & 15;
        const f32x4 v = *(const f32x4*)(W + (size_t)(k0 + kr) * DIM + n0 + nc * 4);
#pragma unroll
        for (int j = 0; j < 4; ++j) {
            short h, l;
            split2(v[j], h, l);
            Th[nc * 4 + j][kr] = h;
            Tl[nc * 4 + j][kr] = l;
        }
    }
    __syncthreads();
#pragma unroll
    for (int i = 0; i < 4; ++i) {
        const int c  = t + 256 * i;
        const int nr = c >> 4;
        const int kc = c & 15;
        *(s16x4*)(WTh + (size_t)(n0 + nr) * DIM + k0 + kc * 4) = *(const s16x4*)&Th[nr][kc * 4];
        *(s16x4*)(WTl + (size_t)(n0 + nr) * DIM + k0 + kc * 4) = *(const s16x4*)&Tl[nr][kc * 4];
    }
}

// ---------------------------------------------------------------------------
// 128x128 split-bf16 MFMA NT core
// ---------------------------------------------------------------------------

DEV_INLINE void mfma128_nt_core(
    const short* __restrict__ Ah, const short* __restrict__ Al, int lda,
    const short* __restrict__ Bh, const short* __restrict__ Bl, int ldb,
    int K, int bm, int bn, f32x4 (&acc)[4][4])
{
    __shared__ __align__(16) short AsH[8][4][16][8];
    __shared__ __align__(16) short AsL[8][4][16][8];
    __shared__ __align__(16) short BsH[8][4][16][8];
    __shared__ __align__(16) short BsL[8][4][16][8];
    const int tid  = threadIdx.x;
    const int lane = tid & 63;
    const int w    = tid >> 6;
    const int wm   = w >> 1, wn = w & 1;
    const int lkg  = lane >> 4, lrow = lane & 15;

    for (int k0 = 0; k0 < K; k0 += 32) {
        bf16x8 vah[2], val[2], vbh[2], vbl[2];
#pragma unroll
        for (int p = 0; p < 2; ++p) {
            const int c = p * 256 + tid;
            const int row = c >> 2, kk = c & 3;
            const size_t ao = (size_t)(bm + row) * lda + k0 + kk * 8;
            const size_t bo = (size_t)(bn + row) * ldb + k0 + kk * 8;
            vah[p] = *(const bf16x8*)(Ah + ao);
            val[p] = *(const bf16x8*)(Al + ao);
            vbh[p] = *(const bf16x8*)(Bh + bo);
            vbl[p] = *(const bf16x8*)(Bl + bo);
        }
        __syncthreads();
#pragma unroll
        for (int p = 0; p < 2; ++p) {
            const int c = p * 256 + tid;
            const int row = c >> 2, kk = c & 3;
            const int fm = row >> 4, rr = row & 15;
            *(bf16x8*)&AsH[fm][kk][rr][0] = vah[p];
            *(bf16x8*)&AsL[fm][kk][rr][0] = val[p];
            *(bf16x8*)&BsH[fm][kk][rr][0] = vbh[p];
            *(bf16x8*)&BsL[fm][kk][rr][0] = vbl[p];
        }
        __syncthreads();

        bf16x8 bhf[4], blf[4];
#pragma unroll
        for (int fn = 0; fn < 4; ++fn) {
            bhf[fn] = *(const bf16x8*)&BsH[wn * 4 + fn][lkg][lrow][0];
            blf[fn] = *(const bf16x8*)&BsL[wn * 4 + fn][lkg][lrow][0];
        }
#pragma unroll
        for (int fm = 0; fm < 4; ++fm) {
            const bf16x8 ah = *(const bf16x8*)&AsH[wm * 4 + fm][lkg][lrow][0];
            const bf16x8 al = *(const bf16x8*)&AsL[wm * 4 + fm][lkg][lrow][0];
#pragma unroll
            for (int fn = 0; fn < 4; ++fn) {
                acc[fm][fn] = __builtin_amdgcn_mfma_f32_16x16x32_bf16(ah, bhf[fn], acc[fm][fn], 0, 0, 0);
                acc[fm][fn] = __builtin_amdgcn_mfma_f32_16x16x32_bf16(ah, blf[fn], acc[fm][fn], 0, 0, 0);
                acc[fm][fn] = __builtin_amdgcn_mfma_f32_16x16x32_bf16(al, bhf[fn], acc[fm][fn], 0, 0, 0);
            }
        }
    }
}

__global__ __launch_bounds__(256) void proj128_kernel(
    const short* __restrict__ Ah, const short* __restrict__ Al, int lda,
    const short* __restrict__ Bh, const short* __restrict__ Bl, int ldb,
    short* __restrict__ Ch, short* __restrict__ Cl, int ldc, int K,
    const float* __restrict__ b0, const float* __restrict__ b1,
    const float* __restrict__ b2)
{
    f32x4 acc[4][4] = {};
    const int bm = blockIdx.x * 128, bn = blockIdx.y * 128;
    mfma128_nt_core(Ah, Al, lda, Bh, Bl, ldb, K, bm, bn, acc);
    const int lane = threadIdx.x & 63;
    const int w = threadIdx.x >> 6;
    const int wm = w >> 1, wn = w & 1;
#pragma unroll
    for (int fm = 0; fm < 4; ++fm)
#pragma unroll
        for (int fn = 0; fn < 4; ++fn) {
            const int col = bn + wn * 64 + fn * 16 + (lane & 15);
            const int seg = col >> 9, cs = col & 511;
            const float bvv = seg == 0 ? b0[cs] : (seg == 1 ? b1[cs] : b2[cs]);
#pragma unroll
            for (int j = 0; j < 4; ++j) {
                const int row = bm + wm * 64 + fm * 16 + (lane >> 4) * 4 + j;
                short h, l;
                split2(acc[fm][fn][j] + bvv, h, l);
                Ch[(size_t)row * ldc + col] = h;
                Cl[(size_t)row * ldc + col] = l;
            }
        }
}

__global__ __launch_bounds__(256) void energy128_kernel(
    const short* __restrict__ QPh, const short* __restrict__ QPl, int lda, int colA0,
    const short* __restrict__ KPh, const short* __restrict__ KPl, int ldb, int colB0,
    float* __restrict__ E, int H, int HD, const float* __restrict__ radd)
{
    const int z = blockIdx.z;
    const int b = z / H;
    const int h = z - b * H;
    const short* Ah = QPh + (size_t)b * QLEN * lda + colA0 + h * HD;
    const short* Al = QPl + (size_t)b * QLEN * lda + colA0 + h * HD;
    const short* Bh = KPh + (size_t)b * KLEN * ldb + colB0 + h * HD;
    const short* Bl = KPl + (size_t)b * KLEN * ldb + colB0 + h * HD;
    float* C = E + (size_t)z * QLEN * KLEN;

    f32x4 acc[4][4] = {};
    const int bm = blockIdx.x * 128, bn = blockIdx.y * 128;
    mfma128_nt_core(Ah, Al, lda, Bh, Bl, ldb, HD, bm, bn, acc);
    const int lane = threadIdx.x & 63;
    const int w = threadIdx.x >> 6;
    const int wm = w >> 1, wn = w & 1;
    const float addv = radd ? radd[0] : 0.0f;
#pragma unroll
    for (int fm = 0; fm < 4; ++fm)
#pragma unroll
        for (int fn = 0; fn < 4; ++fn) {
            const int col = bn + wn * 64 + fn * 16 + (lane & 15);
#pragma unroll
            for (int j = 0; j < 4; ++j) {
                const int row = bm + wm * 64 + fm * 16 + (lane >> 4) * 4 + j;
                C[(size_t)row * KLEN + col] = acc[fm][fn][j] * INV_SCALE + addv;
            }
        }
}

// ---------------------------------------------------------------------------
// 64x64 split-bf16 MFMA NT core (round-12 verified) — out-proj
// ---------------------------------------------------------------------------

DEV_INLINE void mfma_nt_core(const short* __restrict__ Ah, const short* __restrict__ Al, int lda,
                             const short* __restrict__ Bh, const short* __restrict__ Bl, int ldb,
                             int K, int bm, int bn, f32x4 (&acc)[2][2])
{
    __shared__ __align__(16) short AsH[4][4][16][8];
    __shared__ __align__(16) short AsL[4][4][16][8];
    __shared__ __align__(16) short BsH[4][4][16][8];
    __shared__ __align__(16) short BsL[4][4][16][8];
    const int tid  = threadIdx.x;
    const int lane = tid & 63;
    const int w    = tid >> 6;
    const int wm   = w >> 1, wn = w & 1;
    const int r    = tid >> 2;
    const int kg   = tid & 3;
    const int rb   = r >> 4, rr = r & 15;
    const int lkg  = lane >> 4, lrr = lane & 15;

    for (int k0 = 0; k0 < K; k0 += 32) {
        const bf16x8 avh = *(const bf16x8*)(Ah + (size_t)(bm + r) * lda + k0 + kg * 8);
        const bf16x8 avl = *(const bf16x8*)(Al + (size_t)(bm + r) * lda + k0 + kg * 8);
        const bf16x8 bvh = *(const bf16x8*)(Bh + (size_t)(bn + r) * ldb + k0 + kg * 8);
        const bf16x8 bvl = *(const bf16x8*)(Bl + (size_t)(bn + r) * ldb + k0 + kg * 8);
        __syncthreads();
        *(bf16x8*)&AsH[rb][kg][rr][0] = avh;
        *(bf16x8*)&AsL[rb][kg][rr][0] = avl;
        *(bf16x8*)&BsH[rb][kg][rr][0] = bvh;
        *(bf16x8*)&BsL[rb][kg][rr][0] = bvl;
        __syncthreads();
#pragma unroll
        for (int fm = 0; fm < 2; ++fm) {
            const bf16x8 ah = *(const bf16x8*)&AsH[wm * 2 + fm][lkg][lrr][0];
            const bf16x8 al = *(const bf16x8*)&AsL[wm * 2 + fm][lkg][lrr][0];
#pragma unroll
            for (int fn = 0; fn < 2; ++fn) {
                const bf16x8 bh = *(const bf16x8*)&BsH[wn * 2 + fn][lkg][lrr][0];
                const bf16x8 bl = *(const bf16x8*)&BsL[wn * 2 + fn][lkg][lrr][0];
                acc[fm][fn] = __builtin_amdgcn_mfma_f32_16x16x32_bf16(ah, bh, acc[fm][fn], 0, 0, 0);
                acc[fm][fn] = __builtin_amdgcn_mfma_f32_16x16x32_bf16(ah, bl, acc[fm][fn], 0, 0, 0);
                acc[fm][fn] = __builtin_amdgcn_mfma_f32_16x16x32_bf16(al, bh, acc[fm][fn], 0, 0, 0);
            }
        }
    }
}

__global__ __launch_bounds__(256) void mfma_nt_f32_kernel(
    const short* __restrict__ Ah, const short* __restrict__ Al, int lda,
    const short* __restrict__ Bh, const short* __restrict__ Bl, int ldb,
    float* __restrict__ C, int ldc, int K,
    const float* __restrict__ bias)
{
    f32x4 acc[2][2] = {};
    const int bm = blockIdx.x * 64, bn = blockIdx.y * 64;
    mfma_nt_core(Ah, Al, lda, Bh, Bl, ldb, K, bm, bn, acc);
    const int lane = threadIdx.x & 63;
    const int w = threadIdx.x >> 6;
    const int wm = w >> 1, wn = w & 1;
#pragma unroll
    for (int fm = 0; fm < 2; ++fm)
#pragma unroll
        for (int fn = 0; fn < 2; ++fn) {
            const int col = bn + wn * 32 + fn * 16 + (lane & 15);
            const float bvv = bias ? bias[col] : 0.0f;
#pragma unroll
            for (int j = 0; j < 4; ++j) {
                const int row = bm + wm * 32 + fm * 16 + (lane >> 4) * 4 + j;
                C[(size_t)row * ldc + col] = acc[fm][fn][j] + bvv;
            }
        }
}

// ---------------------------------------------------------------------------
// row transforms (round-8 verified)
// ---------------------------------------------------------------------------

__global__ __launch_bounds__(256) void ma_row_kernel(float* __restrict__ PCP,
                                                     float* __restrict__ ICP)
{
    const size_t row = blockIdx.x;
    float* pe = PCP + row * KLEN;
    float* pi = ICP + row * KLEN;
    const int tid = threadIdx.x;
    const int lane = tid & 63, wid = tid >> 6;

    const float4 ev = *(const float4*)(pe + tid * 4);
    float e[4] = {ev.x, ev.y, ev.z, ev.w};
    float p[4], l[4], s[4];
    float run = 0.0f;
#pragma unroll
    for (int j = 0; j < 4; ++j) {
        p[j] = 1.0f / (1.0f + expf(-e[j]));
        float om = 1.0f - p[j];
        om = fminf(fmaxf(om, EPS), 1.0f);
        l[j] = logf(om);
        run += l[j];
        s[j] = run;
    }
    const float t = run;
    float v = t;
#pragma unroll
    for (int off = 1; off < 64; off <<= 1) {
        const float u = __shfl_up(v, off);
        if (lane >= off) v += u;
    }
    __shared__ float wsum[4];
    if (lane == 63) wsum[wid] = v;
    __syncthreads();
    float base = v - t;
    for (int w = 0; w < wid; ++w) base += wsum[w];

    float4 po, io;
    float* pp = (float*)&po;
    float* ip = (float*)&io;
#pragma unroll
    for (int j = 0; j < 4; ++j) {
        const float cum = base + s[j];
        const float cp  = expf(cum - l[j]);
        pp[j] = p[j] * cp;
        ip[j] = 1.0f / fmaxf(cp, EPS);
    }
    *(float4*)(pe + tid * 4) = po;
    *(float4*)(pi + tid * 4) = io;
}

__global__ __launch_bounds__(256) void ca_row_kernel(float* __restrict__ SE,
                                                     float* __restrict__ DEN)
{
    const size_t row = blockIdx.x;
    float* ps = SE + row * KLEN;
    float* pd = DEN + row * KLEN;
    const int tid = threadIdx.x;
    const int lane = tid & 63, wid = tid >> 6;

    const float4 ev = *(const float4*)(ps + tid * 4);
    float e[4] = {ev.x, ev.y, ev.z, ev.w};
    float m = fmaxf(fmaxf(e[0], e[1]), fmaxf(e[2], e[3]));
#pragma unroll
    for (int off = 32; off >= 1; off >>= 1)
        m = fmaxf(m, __shfl_xor(m, off));
    __shared__ float wmax[4];
    if (lane == 0) wmax[wid] = m;
    __syncthreads();
    m = fmaxf(fmaxf(wmax[0], wmax[1]), fmaxf(wmax[2], wmax[3]));

    __shared__ float sh[KLEN + 3];
    if (tid < 3) sh[tid] = 0.0f;
    float se[4];
#pragma unroll
    for (int j = 0; j < 4; ++j) {
        se[j] = fmaxf(expf(e[j] - m), 1e-5f);
        sh[3 + tid * 4 + j] = se[j];
    }
    __syncthreads();
    float4 so, do_;
    float* sp = (float*)&so;
    float* dp = (float*)&do_;
#pragma unroll
    for (int j = 0; j < 4; ++j) {
        const int k = tid * 4 + j;
        sp[j] = se[j];
        dp[j] = sh[3 + k] + sh[2 + k] + sh[1 + k] + sh[k];
    }
    *(float4*)(ps + tid * 4) = so;
    *(float4*)(pd + tid * 4) = do_;
}

// ---------------------------------------------------------------------------
// alpha recurrence, PRODUCER-CONSUMER version.
// Evidence: (a) global_load_lds per-wave queue is shallow (rounds 8/13/14:
// ~1 latency/step regardless of wait discipline); (b) plain global loads
// queue deeply; (c) single-wave DPP scan chain is only ~150cy.
// Design: 5 waves. Waves 0-3 stage rows into a 16-row LDS ring via PLAIN
// loads + ds_writes (compiler-managed waits). Wave 4 runs the round-8
// verified 16-elem/lane scan from LDS. __syncthreads() once per 8-row
// window (64 total) doubles as the producer-write visibility fence.
// Ring layout matches round-8 DMA layout: LDS[c*256+l*4+j] = G[l*16+c*4+j].
// In-place PCP: producers read rows >= 8w+8 while consumer stores 8w..8w+7.
// ---------------------------------------------------------------------------

template<int CTRL, int ROW_MASK>
DEV_INLINE float dpp_add(float x) {
    int t = __builtin_amdgcn_update_dpp(0, __float_as_int(x), CTRL, ROW_MASK, 0xf, true);
    return x + __int_as_float(t);
}

DEV_INLINE float wave64_incl_scan(float x) {
    x = dpp_add<0x111, 0xf>(x);
    x = dpp_add<0x112, 0xf>(x);
    x = dpp_add<0x114, 0xf>(x);
    x = dpp_add<0x118, 0xf>(x);
    x = dpp_add<0x142, 0xa>(x);
    x = dpp_add<0x143, 0xc>(x);
    return x;
}

__global__ __launch_bounds__(320) void alpha_kernel(
    const float* __restrict__ PCPin, const float* __restrict__ ICP,
    float* __restrict__ AOUT)
{
    __shared__ __align__(16) float ring[16][2][1024];   // 128 KB

    const int z = blockIdx.x;
    const float* base  = PCPin + (size_t)z * QLEN * KLEN;
    const float* ibase = ICP   + (size_t)z * QLEN * KLEN;
    float* obase = AOUT + (size_t)z * QLEN * KLEN;
    const int tid  = threadIdx.x;
    const int lane = tid & 63;
    const int wq   = tid >> 6;          // 0..3 producers, 4 consumer

    float a[16];
#pragma unroll
    for (int j = 0; j < 16; ++j) a[j] = 0.0f;
    if (lane == 0) a[0] = 1.0f;

    // prologue: producers stage window 0 (rows 0..7); 16 chunks per wave
    if (wq < 4) {
        f32x4 v[16];
#pragma unroll
        for (int i = 0; i < 16; ++i) {
            const int c = 4 * i + wq;
            const int r = c >> 3, ar = (c >> 2) & 1, qc = c & 3;
            const float* src = (ar ? ibase : base) + (size_t)r * KLEN + lane * 16 + qc * 4;
            v[i] = *(const f32x4*)src;
        }
#pragma unroll
        for (int i = 0; i < 16; ++i) {
            const int c = 4 * i + wq;
            const int r = c >> 3, ar = (c >> 2) & 1, qc = c & 3;
            *(f32x4*)&ring[r][ar][qc * 256 + lane * 4] = v[i];
        }
    }
    __syncthreads();

    for (int w = 0; w < 64; ++w) {
        if (wq < 4) {
            // producers: stage window w+1 (rows 8(w+1)..8(w+1)+7)
            if (w < 63) {
                f32x4 v[16];
#pragma unroll
                for (int i = 0; i < 16; ++i) {
                    const int c = 4 * i + wq;
                    const int r = c >> 3, ar = (c >> 2) & 1, qc = c & 3;
                    const int grow = 8 * (w + 1) + r;
                    const float* src = (ar ? ibase : base) + (size_t)grow * KLEN + lane * 16 + qc * 4;
                    v[i] = *(const f32x4*)src;
                }
#pragma unroll
                for (int i = 0; i < 16; ++i) {
                    const int c = 4 * i + wq;
                    const int r = c >> 3, ar = (c >> 2) & 1, qc = c & 3;
                    const int grow = 8 * (w + 1) + r;
                    *(f32x4*)&ring[grow & 15][ar][qc * 256 + lane * 4] = v[i];
                }
            }
        } else {
            // consumer: rows 8w .. 8w+7 from ring half (w&1)
#pragma unroll
            for (int rr = 0; rr < 8; ++rr) {
                const int q = 8 * w + rr;
                const int slot = q & 15;
                float pc[16], ic[16];
#pragma unroll
                for (int c = 0; c < 4; ++c) {
                    *(f32x4*)&pc[4 * c] = *(const f32x4*)&ring[slot][0][c * 256 + lane * 4];
                    *(f32x4*)&ic[4 * c] = *(const f32x4*)&ring[slot][1][c * 256 + lane * 4];
                }
                float t[16];
#pragma unroll
                for (int j = 0; j < 16; ++j) t[j] = a[j] * ic[j];
                float u1[8], u2[4];
#pragma unroll
                for (int j = 0; j < 8; ++j) u1[j] = t[2 * j] + t[2 * j + 1];
#pragma unroll
                for (int j = 0; j < 4; ++j) u2[j] = u1[2 * j] + u1[2 * j + 1];
                const float tot = (u2[0] + u2[1]) + (u2[2] + u2[3]);
                const float incl = wave64_incl_scan(tot);
                const float excl = incl - tot;
                float s = 0.0f;
#pragma unroll
                for (int j = 0; j < 16; ++j) {
                    s += t[j];
                    a[j] = pc[j] * (excl + s);
                }
                float* st = obase + (size_t)q * KLEN + lane * 16;
#pragma unroll
                for (int c = 0; c < 4; ++c)
                    *(f32x4*)(st + 4 * c) = *(const f32x4*)&a[4 * c];
            }
        }
        __syncthreads();
    }
}

// ---------------------------------------------------------------------------
// fused beta+cv: V read as bf16 pair from the concat K-projection output.
// ---------------------------------------------------------------------------

__global__ __launch_bounds__(256) void fused_cv_kernel(
    const float* __restrict__ ALPHA, const float* __restrict__ SE,
    const float* __restrict__ DEN,
    const short* __restrict__ VPh, const short* __restrict__ VPl, int ldv,
    short* __restrict__ CVh, short* __restrict__ CVl)
{
    const int z = blockIdx.y;          // b*8 + hma*2 + hca
    const int b = z >> 3;
    const int h = z & 7;
    const int hma = h >> 1;
    const int hca = h & 1;
    const int bm = blockIdx.x * 64;

    const float* a_base  = ALPHA + ((size_t)b * H_MA + hma) * QLEN * KLEN;
    const float* se_base = SE  + ((size_t)b * H_CA + hca) * QLEN * KLEN;
    const float* dn_base = DEN + ((size_t)b * H_CA + hca) * QLEN * KLEN;
    const short* vh_base = VPh + (size_t)b * KLEN * ldv + 1024 + h * 64;
    const short* vl_base = VPl + (size_t)b * KLEN * ldv + 1024 + h * 64;
    short* Ch = CVh + (size_t)b * QLEN * DIM + h * 64;
    short* Cl = CVl + (size_t)b * QLEN * DIM + h * 64;

    __shared__ float As[16][68];
    __shared__ float Bs[16][68];
    const int tid  = threadIdx.x;
    const int tm   = (tid >> 4) << 2;
    const int tn   = (tid & 15) << 2;
    const int arow = tid >> 2;
    const int acol = (tid & 3) << 2;
    const int brow = tid >> 4;
    const int bcol = (tid & 15) << 2;
    float acc[4][4] = {};

    for (int k0 = 0; k0 < KLEN; k0 += 16) {
        const int ka = k0 + acol;
        const size_t roff = (size_t)(bm + arow) * KLEN;
        const f32x4 sev = *(const f32x4*)(se_base + roff + ka);
        const f32x4 al0 = *(const f32x4*)(a_base + roff + ka);
        const f32x4 dn0 = *(const f32x4*)(dn_base + roff + ka);
        f32x4 al1 = {0.0f, 0.0f, 0.0f, 0.0f};
        f32x4 dn1 = {1.0f, 1.0f, 1.0f, 1.0f};
        if (ka + 4 < KLEN) {
            al1 = *(const f32x4*)(a_base + roff + ka + 4);
            dn1 = *(const f32x4*)(dn_base + roff + ka + 4);
        }
        float ad[7];
#pragma unroll
        for (int j = 0; j < 4; ++j) ad[j] = al0[j] / dn0[j];
#pragma unroll
        for (int j = 0; j < 3; ++j) ad[4 + j] = al1[j] / dn1[j];
        const s16x4 vh4 = *(const s16x4*)(vh_base + (size_t)(k0 + brow) * ldv + bcol);
        const s16x4 vl4 = *(const s16x4*)(vl_base + (size_t)(k0 + brow) * ldv + bcol);
        __syncthreads();
        As[acol + 0][arow] = sev[0] * (ad[0] + ad[1] + ad[2] + ad[3]);
        As[acol + 1][arow] = sev[1] * (ad[1] + ad[2] + ad[3] + ad[4]);
        As[acol + 2][arow] = sev[2] * (ad[2] + ad[3] + ad[4] + ad[5]);
        As[acol + 3][arow] = sev[3] * (ad[3] + ad[4] + ad[5] + ad[6]);
#pragma unroll
        for (int j = 0; j < 4; ++j)
            Bs[brow][bcol + j] = bf2f(vh4[j]) + bf2f(vl4[j]);
        __syncthreads();
#pragma unroll
        for (int kk = 0; kk < 16; ++kk) {
            const float4 av = *(const float4*)&As[kk][tm];
            const float4 bw = *(const float4*)&Bs[kk][tn];
            const float ar[4] = {av.x, av.y, av.z, av.w};
            const float br[4] = {bw.x, bw.y, bw.z, bw.w};
#pragma unroll
            for (int i = 0; i < 4; ++i)
#pragma unroll
                for (int j = 0; j < 4; ++j)
                    acc[i][j] = fmaf(ar[i], br[j], acc[i][j]);
        }
    }
#pragma unroll
    for (int i = 0; i < 4; ++i) {
        s16x4 oh, ol;
#pragma unroll
        for (int j = 0; j < 4; ++j) {
            short hh, ll;
            split2(acc[i][j], hh, ll);
            oh[j] = hh; ol[j] = ll;
        }
        const size_t ro = (size_t)(bm + tm + i) * DIM + tn;
        *(s16x4*)(Ch + ro) = oh;
        *(s16x4*)(Cl + ro) = ol;
    }
}

// ---------------------------------------------------------------------------

extern "C" void kernel_launch(void* const* d_in, const int* in_sizes, int n_in,
                              void* d_out, int out_size, void* d_ws, size_t ws_size,
                              hipStream_t stream)
{
    (void)in_sizes; (void)n_in; (void)out_size; (void)ws_size;
    const float* key_t = (const float*)d_in[0];
    const float* query = (const float*)d_in[1];
    const float* wk_ma = (const float*)d_in[2];
    const float* bk_ma = (const float*)d_in[3];
    const float* wq_ma = (const float*)d_in[4];
    const float* bq_ma = (const float*)d_in[5];
    const float* r     = (const float*)d_in[6];
    const float* wk_ca = (const float*)d_in[7];
    const float* bk_ca = (const float*)d_in[8];
    const float* wq_ca = (const float*)d_in[9];
    const float* bq_ca = (const float*)d_in[10];
    const float* wv    = (const float*)d_in[11];
    const float* bv    = (const float*)d_in[12];
    const float* wo    = (const float*)d_in[13];
    const float* bo    = (const float*)d_in[14];
    float* out = (float*)d_out;

    // ---- workspace layout: 146 MiB total (unchanged from round 13)
    char* w8 = (char*)d_ws;
    size_t off = 0;
    auto take = [&](size_t n) { char* p = w8 + off; off += n; return p; };
    float* PCP = (float*)take(32ull << 20);
    float* ICP = (float*)take(32ull << 20);
    float* SE  = (float*)take(16ull << 20);
    float* DEN = (float*)take(16ull << 20);
    char* keyrg = take(8ull << 20);
    short* keyh = (short*)keyrg;
    short* keyl = (short*)(keyrg + (4ull << 20));
    short* CVh  = (short*)keyrg;
    short* CVl  = (short*)(keyrg + (2ull << 20));
    short* qh = (short*)take(2ull << 20);
    short* ql = (short*)take(2ull << 20);
    short* WTkh = (short*)take((size_t)1536 * 512 * 2);
    short* WTkl = (short*)take((size_t)1536 * 512 * 2);
    short* WTqh = (short*)take((size_t)1024 * 512 * 2);
    short* WTql = (short*)take((size_t)1024 * 512 * 2);
    short* WToh = (short*)take((size_t)512 * 512 * 2);
    short* WTol = (short*)take((size_t)512 * 512 * 2);
    short* KPh = (short*)take((size_t)4096 * 1536 * 2);
    short* KPl = (short*)take((size_t)4096 * 1536 * 2);
    short* QPh = (short*)take((size_t)2048 * 1024 * 2);
    short* QPl = (short*)take((size_t)2048 * 1024 * 2);

    const dim3 blk(256);
    const size_t KEL = (size_t)B_ * KLEN * DIM;
    const size_t QEL = (size_t)B_ * QLEN * DIM;

    // 1) input/weight conversions
    rowsplit_kernel<<<dim3((int)(KEL / 4 / 256)), blk, 0, stream>>>(key_t, keyh, keyl, (int)(KEL / 4));
    rowsplit_kernel<<<dim3((int)(QEL / 4 / 256)), blk, 0, stream>>>(query, qh, ql, (int)(QEL / 4));
    transsplit_kernel<<<dim3(8, 8), blk, 0, stream>>>(wk_ma, WTkh, WTkl);
    transsplit_kernel<<<dim3(8, 8), blk, 0, stream>>>(wk_ca, WTkh + 512 * 512, WTkl + 512 * 512);
    transsplit_kernel<<<dim3(8, 8), blk, 0, stream>>>(wv, WTkh + 1024 * 512, WTkl + 1024 * 512);
    transsplit_kernel<<<dim3(8, 8), blk, 0, stream>>>(wq_ma, WTqh, WTql);
    transsplit_kernel<<<dim3(8, 8), blk, 0, stream>>>(wq_ca, WTqh + 512 * 512, WTql + 512 * 512);
    transsplit_kernel<<<dim3(8, 8), blk, 0, stream>>>(wo, WToh, WTol);

    // 2) fused projections (128^2 MFMA tiles)
    proj128_kernel<<<dim3(B_ * KLEN / 128, 1536 / 128), blk, 0, stream>>>(
        keyh, keyl, DIM, WTkh, WTkl, DIM, KPh, KPl, 1536, DIM, bk_ma, bk_ca, bv);
    proj128_kernel<<<dim3(B_ * QLEN / 128, 1024 / 128), blk, 0, stream>>>(
        qh, ql, DIM, WTqh, WTql, DIM, QPh, QPl, 1024, DIM, bq_ma, bq_ca, bq_ca);

    // 3) energies (128^2 MFMA tiles)
    energy128_kernel<<<dim3(QLEN / 128, KLEN / 128, B_ * H_MA), blk, 0, stream>>>(
        QPh, QPl, 1024, 0, KPh, KPl, 1536, 0, PCP, H_MA, 128, r);
    energy128_kernel<<<dim3(QLEN / 128, KLEN / 128, B_ * H_CA), blk, 0, stream>>>(
        QPh, QPl, 1024, 512, KPh, KPl, 1536, 512, SE, H_CA, 256, nullptr);

    // 4) row transforms
    ma_row_kernel<<<dim3(B_ * H_MA * QLEN), blk, 0, stream>>>(PCP, ICP);
    ca_row_kernel<<<dim3(B_ * H_CA * QLEN), blk, 0, stream>>>(SE, DEN);

    // 5) monotonic alignment recurrence (producer-consumer, 5 waves)
    alpha_kernel<<<dim3(B_ * H_MA), dim3(320), 0, stream>>>(PCP, ICP, PCP);

    // 6) fused beta+cv (CV emitted as bf16 pair; overlays dead key splits)
    fused_cv_kernel<<<dim3(QLEN / 64, B_ * H_MA * H_CA), blk, 0, stream>>>(
        PCP, SE, DEN, KPh, KPl, 1536, CVh, CVl);

    // 7) output projection (64^2 MFMA, 256 blocks)
    mfma_nt_f32_kernel<<<dim3(B_ * QLEN / 64, DIM / 64), blk, 0, stream>>>(
        CVh, CVl, DIM, WToh, WTol, DIM, out, DIM, DIM, bo);
}

// Round 17
// 361.321 us; speedup vs baseline: 1.1828x; 1.1828x over previous
//
#include <hip/hip_runtime.h>
#include <hip/hip_bf16.h>
#include <math.h>

#define DEV_INLINE __device__ __forceinline__

typedef float f32x4 __attribute__((ext_vector_type(4)));
typedef short bf16x8 __attribute__((ext_vector_type(8)));
typedef short s16x4 __attribute__((ext_vector_type(4)));

constexpr int B_    = 4;
constexpr int QLEN  = 512;
constexpr int KLEN  = 1024;
constexpr int DIM   = 512;
constexpr int H_MA  = 4;
constexpr int H_CA  = 2;
constexpr int CHUNK = 4;
constexpr float EPS = 1e-6f;
constexpr float INV_SCALE = 1.0f / 22.62741699796952f;  // 1/sqrt(512)

// ---------------------------------------------------------------------------
// fp32 -> bf16 hi/lo split (RNE both halves; a ~= hi + lo)
// ---------------------------------------------------------------------------

DEV_INLINE unsigned short f2bf(float x) {
    unsigned int u = __float_as_uint(x);
    unsigned int r = u + 0x7FFFu + ((u >> 16) & 1u);
    return (unsigned short)(r >> 16);
}

DEV_INLINE void split2(float x, short& h, short& l) {
    const unsigned short hb = f2bf(x);
    const float hf = __uint_as_float(((unsigned int)hb) << 16);
    h = (short)hb;
    l = (short)f2bf(x - hf);
}

DEV_INLINE float bf2f(short s) {
    return __uint_as_float(((unsigned int)(unsigned short)s) << 16);
}

__global__ __launch_bounds__(256) void rowsplit_kernel(
    const float* __restrict__ X, short* __restrict__ Xh,
    short* __restrict__ Xl, int n4)
{
    const int i = blockIdx.x * 256 + threadIdx.x;
    if (i >= n4) return;
    const f32x4 v = *(const f32x4*)(X + (size_t)i * 4);
    s16x4 h, l;
#pragma unroll
    for (int j = 0; j < 4; ++j) {
        short hh, ll;
        split2(v[j], hh, ll);
        h[j] = hh; l[j] = ll;
    }
    *(s16x4*)(Xh + (size_t)i * 4) = h;
    *(s16x4*)(Xl + (size_t)i * 4) = l;
}

// 6 weight matrices fp32[512,512] -> transposed bf16 pairs, one launch
__global__ __launch_bounds__(256) void transsplit6_kernel(
    const float* __restrict__ w0, const float* __restrict__ w1,
    const float* __restrict__ w2, const float* __restrict__ w3,
    const float* __restrict__ w4, const float* __restrict__ w5,
    short* __restrict__ WTkh, short* __restrict__ WTkl,
    short* __restrict__ WTqh, short* __restrict__ WTql,
    short* __restrict__ WToh, short* __restrict__ WTol)
{
    const float* W; short* Dh; short* Dl;
    const int zz = blockIdx.z;
    const int MS = 512 * 512;
    switch (zz) {
        case 0: W = w0; Dh = WTkh;          Dl = WTkl;          break;
        case 1: W = w1; Dh = WTkh + MS;     Dl = WTkl + MS;     break;
        case 2: W = w2; Dh = WTkh + 2 * MS; Dl = WTkl + 2 * MS; break;
        case 3: W = w3; Dh = WTqh;          Dl = WTql;          break;
        case 4: W = w4; Dh = WTqh + MS;     Dl = WTql + MS;     break;
        default: W = w5; Dh = WToh;         Dl = WTol;          break;
    }

    __shared__ __align__(16) short Th[64][72];
    __shared__ __align__(16) short Tl[64][72];
    const int t = threadIdx.x;
    const int k0 = blockIdx.x * 64;
    const int n0 = blockIdx.y * 64;
#pragma unroll
    for (int i = 0; i < 4; ++i) {
        const int c  = t + 256 * i;
        const int kr = c >> 4;
        const int nc = c & 15;
        const f32x4 v = *(const f32x4*)(W + (size_t)(k0 + kr) * DIM + n0 + nc * 4);
#pragma unroll
        for (int j = 0; j < 4; ++j) {
            short h, l;
            split2(v[j], h, l);
            Th[nc * 4 + j][kr] = h;
            Tl[nc * 4 + j][kr] = l;
        }
    }
    __syncthreads();
#pragma unroll
    for (int i = 0; i < 4; ++i) {
        const int c  = t + 256 * i;
        const int nr = c >> 4;
        const int kc = c & 15;
        *(s16x4*)(Dh + (size_t)(n0 + nr) * DIM + k0 + kc * 4) = *(const s16x4*)&Th[nr][kc * 4];
        *(s16x4*)(Dl + (size_t)(n0 + nr) * DIM + k0 + kc * 4) = *(const s16x4*)&Tl[nr][kc * 4];
    }
}

// ---------------------------------------------------------------------------
// 128x128 split-bf16 MFMA NT core
// ---------------------------------------------------------------------------

DEV_INLINE void mfma128_nt_core(
    const short* __restrict__ Ah, const short* __restrict__ Al, int lda,
    const short* __restrict__ Bh, const short* __restrict__ Bl, int ldb,
    int K, int bm, int bn, f32x4 (&acc)[4][4])
{
    __shared__ __align__(16) short AsH[8][4][16][8];
    __shared__ __align__(16) short AsL[8][4][16][8];
    __shared__ __align__(16) short BsH[8][4][16][8];
    __shared__ __align__(16) short BsL[8][4][16][8];
    const int tid  = threadIdx.x;
    const int lane = tid & 63;
    const int w    = tid >> 6;
    const int wm   = w >> 1, wn = w & 1;
    const int lkg  = lane >> 4, lrow = lane & 15;

    for (int k0 = 0; k0 < K; k0 += 32) {
        bf16x8 vah[2], val[2], vbh[2], vbl[2];
#pragma unroll
        for (int p = 0; p < 2; ++p) {
            const int c = p * 256 + tid;
            const int row = c >> 2, kk = c & 3;
            const size_t ao = (size_t)(bm + row) * lda + k0 + kk * 8;
            const size_t bo = (size_t)(bn + row) * ldb + k0 + kk * 8;
            vah[p] = *(const bf16x8*)(Ah + ao);
            val[p] = *(const bf16x8*)(Al + ao);
            vbh[p] = *(const bf16x8*)(Bh + bo);
            vbl[p] = *(const bf16x8*)(Bl + bo);
        }
        __syncthreads();
#pragma unroll
        for (int p = 0; p < 2; ++p) {
            const int c = p * 256 + tid;
            const int row = c >> 2, kk = c & 3;
            const int fm = row >> 4, rr = row & 15;
            *(bf16x8*)&AsH[fm][kk][rr][0] = vah[p];
            *(bf16x8*)&AsL[fm][kk][rr][0] = val[p];
            *(bf16x8*)&BsH[fm][kk][rr][0] = vbh[p];
            *(bf16x8*)&BsL[fm][kk][rr][0] = vbl[p];
        }
        __syncthreads();

        bf16x8 bhf[4], blf[4];
#pragma unroll
        for (int fn = 0; fn < 4; ++fn) {
            bhf[fn] = *(const bf16x8*)&BsH[wn * 4 + fn][lkg][lrow][0];
            blf[fn] = *(const bf16x8*)&BsL[wn * 4 + fn][lkg][lrow][0];
        }
#pragma unroll
        for (int fm = 0; fm < 4; ++fm) {
            const bf16x8 ah = *(const bf16x8*)&AsH[wm * 4 + fm][lkg][lrow][0];
            const bf16x8 al = *(const bf16x8*)&AsL[wm * 4 + fm][lkg][lrow][0];
#pragma unroll
            for (int fn = 0; fn < 4; ++fn) {
                acc[fm][fn] = __builtin_amdgcn_mfma_f32_16x16x32_bf16(ah, bhf[fn], acc[fm][fn], 0, 0, 0);
                acc[fm][fn] = __builtin_amdgcn_mfma_f32_16x16x32_bf16(ah, blf[fn], acc[fm][fn], 0, 0, 0);
                acc[fm][fn] = __builtin_amdgcn_mfma_f32_16x16x32_bf16(al, bhf[fn], acc[fm][fn], 0, 0, 0);
            }
        }
    }
}

__global__ __launch_bounds__(256) void proj128_kernel(
    const short* __restrict__ Ah, const short* __restrict__ Al, int lda,
    const short* __restrict__ Bh, const short* __restrict__ Bl, int ldb,
    short* __restrict__ Ch, short* __restrict__ Cl, int ldc, int K,
    const float* __restrict__ b0, const float* __restrict__ b1,
    const float* __restrict__ b2)
{
    f32x4 acc[4][4] = {};
    const int bm = blockIdx.x * 128, bn = blockIdx.y * 128;
    mfma128_nt_core(Ah, Al, lda, Bh, Bl, ldb, K, bm, bn, acc);
    const int lane = threadIdx.x & 63;
    const int w = threadIdx.x >> 6;
    const int wm = w >> 1, wn = w & 1;
#pragma unroll
    for (int fm = 0; fm < 4; ++fm)
#pragma unroll
        for (int fn = 0; fn < 4; ++fn) {
            const int col = bn + wn * 64 + fn * 16 + (lane & 15);
            const int seg = col >> 9, cs = col & 511;
            const float bvv = seg == 0 ? b0[cs] : (seg == 1 ? b1[cs] : b2[cs]);
#pragma unroll
            for (int j = 0; j < 4; ++j) {
                const int row = bm + wm * 64 + fm * 16 + (lane >> 4) * 4 + j;
                short h, l;
                split2(acc[fm][fn][j] + bvv, h, l);
                Ch[(size_t)row * ldc + col] = h;
                Cl[(size_t)row * ldc + col] = l;
            }
        }
}

__global__ __launch_bounds__(256) void energy128_kernel(
    const short* __restrict__ QPh, const short* __restrict__ QPl, int lda, int colA0,
    const short* __restrict__ KPh, const short* __restrict__ KPl, int ldb, int colB0,
    float* __restrict__ E, int H, int HD, const float* __restrict__ radd)
{
    const int z = blockIdx.z;
    const int b = z / H;
    const int h = z - b * H;
    const short* Ah = QPh + (size_t)b * QLEN * lda + colA0 + h * HD;
    const short* Al = QPl + (size_t)b * QLEN * lda + colA0 + h * HD;
    const short* Bh = KPh + (size_t)b * KLEN * ldb + colB0 + h * HD;
    const short* Bl = KPl + (size_t)b * KLEN * ldb + colB0 + h * HD;
    float* C = E + (size_t)z * QLEN * KLEN;

    f32x4 acc[4][4] = {};
    const int bm = blockIdx.x * 128, bn = blockIdx.y * 128;
    mfma128_nt_core(Ah, Al, lda, Bh, Bl, ldb, HD, bm, bn, acc);
    const int lane = threadIdx.x & 63;
    const int w = threadIdx.x >> 6;
    const int wm = w >> 1, wn = w & 1;
    const float addv = radd ? radd[0] : 0.0f;
#pragma unroll
    for (int fm = 0; fm < 4; ++fm)
#pragma unroll
        for (int fn = 0; fn < 4; ++fn) {
            const int col = bn + wn * 64 + fn * 16 + (lane & 15);
#pragma unroll
            for (int j = 0; j < 4; ++j) {
                const int row = bm + wm * 64 + fm * 16 + (lane >> 4) * 4 + j;
                C[(size_t)row * KLEN + col] = acc[fm][fn][j] * INV_SCALE + addv;
            }
        }
}

// ---------------------------------------------------------------------------
// 64x64 split-bf16 MFMA NT core (round-12 verified) — out-proj
// ---------------------------------------------------------------------------

DEV_INLINE void mfma_nt_core(const short* __restrict__ Ah, const short* __restrict__ Al, int lda,
                             const short* __restrict__ Bh, const short* __restrict__ Bl, int ldb,
                             int K, int bm, int bn, f32x4 (&acc)[2][2])
{
    __shared__ __align__(16) short AsH[4][4][16][8];
    __shared__ __align__(16) short AsL[4][4][16][8];
    __shared__ __align__(16) short BsH[4][4][16][8];
    __shared__ __align__(16) short BsL[4][4][16][8];
    const int tid  = threadIdx.x;
    const int lane = tid & 63;
    const int w    = tid >> 6;
    const int wm   = w >> 1, wn = w & 1;
    const int r    = tid >> 2;
    const int kg   = tid & 3;
    const int rb   = r >> 4, rr = r & 15;
    const int lkg  = lane >> 4, lrr = lane & 15;

    for (int k0 = 0; k0 < K; k0 += 32) {
        const bf16x8 avh = *(const bf16x8*)(Ah + (size_t)(bm + r) * lda + k0 + kg * 8);
        const bf16x8 avl = *(const bf16x8*)(Al + (size_t)(bm + r) * lda + k0 + kg * 8);
        const bf16x8 bvh = *(const bf16x8*)(Bh + (size_t)(bn + r) * ldb + k0 + kg * 8);
        const bf16x8 bvl = *(const bf16x8*)(Bl + (size_t)(bn + r) * ldb + k0 + kg * 8);
        __syncthreads();
        *(bf16x8*)&AsH[rb][kg][rr][0] = avh;
        *(bf16x8*)&AsL[rb][kg][rr][0] = avl;
        *(bf16x8*)&BsH[rb][kg][rr][0] = bvh;
        *(bf16x8*)&BsL[rb][kg][rr][0] = bvl;
        __syncthreads();
#pragma unroll
        for (int fm = 0; fm < 2; ++fm) {
            const bf16x8 ah = *(const bf16x8*)&AsH[wm * 2 + fm][lkg][lrr][0];
            const bf16x8 al = *(const bf16x8*)&AsL[wm * 2 + fm][lkg][lrr][0];
#pragma unroll
            for (int fn = 0; fn < 2; ++fn) {
                const bf16x8 bh = *(const bf16x8*)&BsH[wn * 2 + fn][lkg][lrr][0];
                const bf16x8 bl = *(const bf16x8*)&BsL[wn * 2 + fn][lkg][lrr][0];
                acc[fm][fn] = __builtin_amdgcn_mfma_f32_16x16x32_bf16(ah, bh, acc[fm][fn], 0, 0, 0);
                acc[fm][fn] = __builtin_amdgcn_mfma_f32_16x16x32_bf16(ah, bl, acc[fm][fn], 0, 0, 0);
                acc[fm][fn] = __builtin_amdgcn_mfma_f32_16x16x32_bf16(al, bh, acc[fm][fn], 0, 0, 0);
            }
        }
    }
}

__global__ __launch_bounds__(256) void mfma_nt_f32_kernel(
    const short* __restrict__ Ah, const short* __restrict__ Al, int lda,
    const short* __restrict__ Bh, const short* __restrict__ Bl, int ldb,
    float* __restrict__ C, int ldc, int K,
    const float* __restrict__ bias)
{
    f32x4 acc[2][2] = {};
    const int bm = blockIdx.x * 64, bn = blockIdx.y * 64;
    mfma_nt_core(Ah, Al, lda, Bh, Bl, ldb, K, bm, bn, acc);
    const int lane = threadIdx.x & 63;
    const int w = threadIdx.x >> 6;
    const int wm = w >> 1, wn = w & 1;
#pragma unroll
    for (int fm = 0; fm < 2; ++fm)
#pragma unroll
        for (int fn = 0; fn < 2; ++fn) {
            const int col = bn + wn * 32 + fn * 16 + (lane & 15);
            const float bvv = bias ? bias[col] : 0.0f;
#pragma unroll
            for (int j = 0; j < 4; ++j) {
                const int row = bm + wm * 32 + fm * 16 + (lane >> 4) * 4 + j;
                C[(size_t)row * ldc + col] = acc[fm][fn][j] + bvv;
            }
        }
}

// ---------------------------------------------------------------------------
// row transforms. ca_row now stores RDEN = 1/moving_sum (fused_cv multiplies).
// ---------------------------------------------------------------------------

__global__ __launch_bounds__(256) void ma_row_kernel(float* __restrict__ PCP,
                                                     float* __restrict__ ICP)
{
    const size_t row = blockIdx.x;
    float* pe = PCP + row * KLEN;
    float* pi = ICP + row * KLEN;
    const int tid = threadIdx.x;
    const int lane = tid & 63, wid = tid >> 6;

    const float4 ev = *(const float4*)(pe + tid * 4);
    float e[4] = {ev.x, ev.y, ev.z, ev.w};
    float p[4], l[4], s[4];
    float run = 0.0f;
#pragma unroll
    for (int j = 0; j < 4; ++j) {
        p[j] = 1.0f / (1.0f + expf(-e[j]));
        float om = 1.0f - p[j];
        om = fminf(fmaxf(om, EPS), 1.0f);
        l[j] = logf(om);
        run += l[j];
        s[j] = run;
    }
    const float t = run;
    float v = t;
#pragma unroll
    for (int off = 1; off < 64; off <<= 1) {
        const float u = __shfl_up(v, off);
        if (lane >= off) v += u;
    }
    __shared__ float wsum[4];
    if (lane == 63) wsum[wid] = v;
    __syncthreads();
    float base = v - t;
    for (int w = 0; w < wid; ++w) base += wsum[w];

    float4 po, io;
    float* pp = (float*)&po;
    float* ip = (float*)&io;
#pragma unroll
    for (int j = 0; j < 4; ++j) {
        const float cum = base + s[j];
        const float cp  = expf(cum - l[j]);
        pp[j] = p[j] * cp;
        ip[j] = 1.0f / fmaxf(cp, EPS);
    }
    *(float4*)(pe + tid * 4) = po;
    *(float4*)(pi + tid * 4) = io;
}

__global__ __launch_bounds__(256) void ca_row_kernel(float* __restrict__ SE,
                                                     float* __restrict__ RDEN)
{
    const size_t row = blockIdx.x;
    float* ps = SE + row * KLEN;
    float* pd = RDEN + row * KLEN;
    const int tid = threadIdx.x;
    const int lane = tid & 63, wid = tid >> 6;

    const float4 ev = *(const float4*)(ps + tid * 4);
    float e[4] = {ev.x, ev.y, ev.z, ev.w};
    float m = fmaxf(fmaxf(e[0], e[1]), fmaxf(e[2], e[3]));
#pragma unroll
    for (int off = 32; off >= 1; off >>= 1)
        m = fmaxf(m, __shfl_xor(m, off));
    __shared__ float wmax[4];
    if (lane == 0) wmax[wid] = m;
    __syncthreads();
    m = fmaxf(fmaxf(wmax[0], wmax[1]), fmaxf(wmax[2], wmax[3]));

    __shared__ float sh[KLEN + 3];
    if (tid < 3) sh[tid] = 0.0f;
    float se[4];
#pragma unroll
    for (int j = 0; j < 4; ++j) {
        se[j] = fmaxf(expf(e[j] - m), 1e-5f);
        sh[3 + tid * 4 + j] = se[j];
    }
    __syncthreads();
    float4 so, do_;
    float* sp = (float*)&so;
    float* dp = (float*)&do_;
#pragma unroll
    for (int j = 0; j < 4; ++j) {
        const int k = tid * 4 + j;
        sp[j] = se[j];
        dp[j] = 1.0f / (sh[3 + k] + sh[2 + k] + sh[1 + k] + sh[k]);
    }
    *(float4*)(ps + tid * 4) = so;
    *(float4*)(pd + tid * 4) = do_;
}

// ---------------------------------------------------------------------------
// alpha recurrence — ROUND-15 4-WAVE VERSION (verified, 131 us). Waves split
// the k-row into quarters (2 DMAs + 2 ds_reads + 1 store per wave per step);
// hierarchical scan with one raw s_barrier (not __syncthreads) per step.
// ---------------------------------------------------------------------------

template<int CTRL, int ROW_MASK>
DEV_INLINE float dpp_add(float x) {
    int t = __builtin_amdgcn_update_dpp(0, __float_as_int(x), CTRL, ROW_MASK, 0xf, true);
    return x + __int_as_float(t);
}

DEV_INLINE float wave64_incl_scan(float x) {
    x = dpp_add<0x111, 0xf>(x);
    x = dpp_add<0x112, 0xf>(x);
    x = dpp_add<0x114, 0xf>(x);
    x = dpp_add<0x118, 0xf>(x);
    x = dpp_add<0x142, 0xa>(x);
    x = dpp_add<0x143, 0xc>(x);
    return x;
}

typedef __attribute__((address_space(3))) void lv_t;
typedef __attribute__((address_space(1))) const void gv_t;

DEV_INLINE void dma16(const float* g, float* l) {
    __builtin_amdgcn_global_load_lds((gv_t*)g, (lv_t*)l, 16, 0, 0);
}

template<int N> DEV_INLINE void vwait() {
    asm volatile("s_waitcnt vmcnt(%0)" :: "i"(N) : "memory");
    __builtin_amdgcn_sched_barrier(0);
}

template<int N> DEV_INLINE void lwait() {
    asm volatile("s_waitcnt lgkmcnt(%0)" :: "i"(N));
    __builtin_amdgcn_sched_barrier(0);
}

DEV_INLINE void ldsr4(f32x4& d, const float* a_) {
    const unsigned off = (unsigned)(size_t)(lv_t*)a_;
    asm volatile("ds_read_b128 %0, %1" : "=v"(d) : "v"(off));
}

DEV_INLINE void dswr1(float* a_, float v) {
    const unsigned off = (unsigned)(size_t)(lv_t*)a_;
    asm volatile("ds_write_b32 %0, %1" :: "v"(off), "v"(v));
}

DEV_INLINE void sbar() {
    asm volatile("s_barrier" ::: "memory");
}

#define ASTEP(WAITN, BUF, NBUF, PAR, DO_READ, DO_DMA, CG, NG)         \
    {                                                                 \
        vwait<WAITN>();                                               \
        if (DO_READ) {                                                \
            ldsr4(p##NG, &ring[NBUF][0][qoff]);                       \
            ldsr4(i##NG, &ring[NBUF][1][qoff]);                       \
        }                                                             \
        const float t0 = a0 * i##CG[0];                               \
        const float t1 = a1 * i##CG[1];                               \
        const float t2 = a2 * i##CG[2];                               \
        const float t3 = a3 * i##CG[3];                               \
        const float s1 = t0 + t1;                                     \
        const float s2 = s1 + t2;                                     \
        const float s3 = s2 + t3;                                     \
        const float incl = wave64_incl_scan(s3);                      \
        const float excl = incl - s3;                                 \
        if (lane == 63) dswr1(&tot[PAR][wq], incl);                   \
        lwait<0>();                                                   \
        sbar();                                                       \
        f32x4 T;                                                      \
        ldsr4(T, &tot[PAR][0]);                                       \
        lwait<0>();                                                   \
        float Tpre = excl;                                            \
        if (wq > 0) Tpre += T[0];                                     \
        if (wq > 1) Tpre += T[1];                                     \
        if (wq > 2) Tpre += T[2];                                     \
        a0 = p##CG[0] * (Tpre + t0);                                  \
        a1 = p##CG[1] * (Tpre + s1);                                  \
        a2 = p##CG[2] * (Tpre + s2);                                  \
        a3 = p##CG[3] * (Tpre + s3);                                  \
        f32x4 av = {a0, a1, a2, a3};                                  \
        *(f32x4*)st = av;                                             \
        st += KLEN;                                                   \
        __builtin_amdgcn_sched_barrier(0);                            \
        if (DO_DMA) {                                                 \
            dma16(np, &ring[BUF][0][wq * 256]);                       \
            dma16(ni, &ring[BUF][1][wq * 256]);                       \
            np += KLEN; ni += KLEN;                                   \
        }                                                             \
    }

__global__ __launch_bounds__(256) void alpha_kernel(
    const float* __restrict__ PCPin, const float* __restrict__ ICP,
    float* __restrict__ AOUT)
{
    __shared__ __align__(16) float ring[8][2][1024];   // 64 KB
    __shared__ __align__(16) float tot[2][4];          // ping-pong wave totals

    const int z = blockIdx.x;
    const float* base = PCPin + (size_t)z * QLEN * KLEN;
    const float* ibase = ICP + (size_t)z * QLEN * KLEN;
    float* obase = AOUT + (size_t)z * QLEN * KLEN;
    const int tid  = threadIdx.x;
    const int lane = tid & 63;
    const int wq   = tid >> 6;
    const int qoff = wq * 256 + lane * 4;

    {
        const float* pp = base + qoff;
        const float* ip = ibase + qoff;
#pragma unroll
        for (int rr = 0; rr < 8; ++rr) {
            dma16(pp, &ring[rr][0][wq * 256]);
            dma16(ip, &ring[rr][1][wq * 256]);
            pp += KLEN; ip += KLEN;
        }
    }

    f32x4 pA, iA, pB, iB;
    vwait<14>();
    ldsr4(pA, &ring[0][0][qoff]);
    ldsr4(iA, &ring[0][1][qoff]);
    lwait<0>();

    float a0 = 0.0f, a1 = 0.0f, a2 = 0.0f, a3 = 0.0f;
    if (qoff == 0) a0 = 1.0f;

    float* st = obase + qoff;
    const float* np = base + (size_t)8 * KLEN + qoff;
    const float* ni = ibase + (size_t)8 * KLEN + qoff;

    for (int it = 0; it < 63; ++it) {
        ASTEP(12, 0, 1, 0, true, true, A, B)
        ASTEP(12, 1, 2, 1, true, true, B, A)
        ASTEP(12, 2, 3, 0, true, true, A, B)
        ASTEP(12, 3, 4, 1, true, true, B, A)
        ASTEP(12, 4, 5, 0, true, true, A, B)
        ASTEP(12, 5, 6, 1, true, true, B, A)
        ASTEP(12, 6, 7, 0, true, true, A, B)
        ASTEP(12, 7, 0, 1, true, true, B, A)
    }

    ASTEP(12, 0, 1, 0, true, false, A, B)
    ASTEP(10, 1, 2, 1, true, false, B, A)
    ASTEP(8,  2, 3, 0, true, false, A, B)
    ASTEP(6,  3, 4, 1, true, false, B, A)
    ASTEP(4,  4, 5, 0, true, false, A, B)
    ASTEP(2,  5, 6, 1, true, false, B, A)
    ASTEP(0,  6, 7, 0, true, false, A, B)
    ASTEP(0,  7, 0, 1, false, false, B, A)
}

// ---------------------------------------------------------------------------
// fused beta+cv: RDEN holds reciprocals (multiply, not divide).
// ---------------------------------------------------------------------------

__global__ __launch_bounds__(256) void fused_cv_kernel(
    const float* __restrict__ ALPHA, const float* __restrict__ SE,
    const float* __restrict__ RDEN,
    const short* __restrict__ VPh, const short* __restrict__ VPl, int ldv,
    short* __restrict__ CVh, short* __restrict__ CVl)
{
    const int z = blockIdx.y;          // b*8 + hma*2 + hca
    const int b = z >> 3;
    const int h = z & 7;
    const int hma = h >> 1;
    const int hca = h & 1;
    const int bm = blockIdx.x * 64;

    const float* a_base  = ALPHA + ((size_t)b * H_MA + hma) * QLEN * KLEN;
    const float* se_base = SE   + ((size_t)b * H_CA + hca) * QLEN * KLEN;
    const float* dn_base = RDEN + ((size_t)b * H_CA + hca) * QLEN * KLEN;
    const short* vh_base = VPh + (size_t)b * KLEN * ldv + 1024 + h * 64;
    const short* vl_base = VPl + (size_t)b * KLEN * ldv + 1024 + h * 64;
    short* Ch = CVh + (size_t)b * QLEN * DIM + h * 64;
    short* Cl = CVl + (size_t)b * QLEN * DIM + h * 64;

    __shared__ float As[16][68];
    __shared__ float Bs[16][68];
    const int tid  = threadIdx.x;
    const int tm   = (tid >> 4) << 2;
    const int tn   = (tid & 15) << 2;
    const int arow = tid >> 2;
    const int acol = (tid & 3) << 2;
    const int brow = tid >> 4;
    const int bcol = (tid & 15) << 2;
    float acc[4][4] = {};

    for (int k0 = 0; k0 < KLEN; k0 += 16) {
        const int ka = k0 + acol;
        const size_t roff = (size_t)(bm + arow) * KLEN;
        const f32x4 sev = *(const f32x4*)(se_base + roff + ka);
        const f32x4 al0 = *(const f32x4*)(a_base + roff + ka);
        const f32x4 dn0 = *(const f32x4*)(dn_base + roff + ka);
        f32x4 al1 = {0.0f, 0.0f, 0.0f, 0.0f};
        f32x4 dn1 = {1.0f, 1.0f, 1.0f, 1.0f};
        if (ka + 4 < KLEN) {
            al1 = *(const f32x4*)(a_base + roff + ka + 4);
            dn1 = *(const f32x4*)(dn_base + roff + ka + 4);
        }
        float ad[7];
#pragma unroll
        for (int j = 0; j < 4; ++j) ad[j] = al0[j] * dn0[j];
#pragma unroll
        for (int j = 0; j < 3; ++j) ad[4 + j] = al1[j] * dn1[j];
        const s16x4 vh4 = *(const s16x4*)(vh_base + (size_t)(k0 + brow) * ldv + bcol);
        const s16x4 vl4 = *(const s16x4*)(vl_base + (size_t)(k0 + brow) * ldv + bcol);
        __syncthreads();
        As[acol + 0][arow] = sev[0] * (ad[0] + ad[1] + ad[2] + ad[3]);
        As[acol + 1][arow] = sev[1] * (ad[1] + ad[2] + ad[3] + ad[4]);
        As[acol + 2][arow] = sev[2] * (ad[2] + ad[3] + ad[4] + ad[5]);
        As[acol + 3][arow] = sev[3] * (ad[3] + ad[4] + ad[5] + ad[6]);
#pragma unroll
        for (int j = 0; j < 4; ++j)
            Bs[brow][bcol + j] = bf2f(vh4[j]) + bf2f(vl4[j]);
        __syncthreads();
#pragma unroll
        for (int kk = 0; kk < 16; ++kk) {
            const float4 av = *(const float4*)&As[kk][tm];
            const float4 bw = *(const float4*)&Bs[kk][tn];
            const float ar[4] = {av.x, av.y, av.z, av.w};
            const float br[4] = {bw.x, bw.y, bw.z, bw.w};
#pragma unroll
            for (int i = 0; i < 4; ++i)
#pragma unroll
                for (int j = 0; j < 4; ++j)
                    acc[i][j] = fmaf(ar[i], br[j], acc[i][j]);
        }
    }
#pragma unroll
    for (int i = 0; i < 4; ++i) {
        s16x4 oh, ol;
#pragma unroll
        for (int j = 0; j < 4; ++j) {
            short hh, ll;
            split2(acc[i][j], hh, ll);
            oh[j] = hh; ol[j] = ll;
        }
        const size_t ro = (size_t)(bm + tm + i) * DIM + tn;
        *(s16x4*)(Ch + ro) = oh;
        *(s16x4*)(Cl + ro) = ol;
    }
}

// ---------------------------------------------------------------------------

extern "C" void kernel_launch(void* const* d_in, const int* in_sizes, int n_in,
                              void* d_out, int out_size, void* d_ws, size_t ws_size,
                              hipStream_t stream)
{
    (void)in_sizes; (void)n_in; (void)out_size; (void)ws_size;
    const float* key_t = (const float*)d_in[0];
    const float* query = (const float*)d_in[1];
    const float* wk_ma = (const float*)d_in[2];
    const float* bk_ma = (const float*)d_in[3];
    const float* wq_ma = (const float*)d_in[4];
    const float* bq_ma = (const float*)d_in[5];
    const float* r     = (const float*)d_in[6];
    const float* wk_ca = (const float*)d_in[7];
    const float* bk_ca = (const float*)d_in[8];
    const float* wq_ca = (const float*)d_in[9];
    const float* bq_ca = (const float*)d_in[10];
    const float* wv    = (const float*)d_in[11];
    const float* bv    = (const float*)d_in[12];
    const float* wo    = (const float*)d_in[13];
    const float* bo    = (const float*)d_in[14];
    float* out = (float*)d_out;

    // ---- workspace layout: 146 MiB total
    char* w8 = (char*)d_ws;
    size_t off = 0;
    auto take = [&](size_t n) { char* p = w8 + off; off += n; return p; };
    float* PCP = (float*)take(32ull << 20);
    float* ICP = (float*)take(32ull << 20);
    float* SE  = (float*)take(16ull << 20);
    float* DEN = (float*)take(16ull << 20);
    char* keyrg = take(8ull << 20);
    short* keyh = (short*)keyrg;
    short* keyl = (short*)(keyrg + (4ull << 20));
    short* CVh  = (short*)keyrg;
    short* CVl  = (short*)(keyrg + (2ull << 20));
    short* qh = (short*)take(2ull << 20);
    short* ql = (short*)take(2ull << 20);
    short* WTkh = (short*)take((size_t)1536 * 512 * 2);
    short* WTkl = (short*)take((size_t)1536 * 512 * 2);
    short* WTqh = (short*)take((size_t)1024 * 512 * 2);
    short* WTql = (short*)take((size_t)1024 * 512 * 2);
    short* WToh = (short*)take((size_t)512 * 512 * 2);
    short* WTol = (short*)take((size_t)512 * 512 * 2);
    short* KPh = (short*)take((size_t)4096 * 1536 * 2);
    short* KPl = (short*)take((size_t)4096 * 1536 * 2);
    short* QPh = (short*)take((size_t)2048 * 1024 * 2);
    short* QPl = (short*)take((size_t)2048 * 1024 * 2);

    const dim3 blk(256);
    const size_t KEL = (size_t)B_ * KLEN * DIM;
    const size_t QEL = (size_t)B_ * QLEN * DIM;

    // 1) input/weight conversions (transsplit merged into one launch)
    rowsplit_kernel<<<dim3((int)(KEL / 4 / 256)), blk, 0, stream>>>(key_t, keyh, keyl, (int)(KEL / 4));
    rowsplit_kernel<<<dim3((int)(QEL / 4 / 256)), blk, 0, stream>>>(query, qh, ql, (int)(QEL / 4));
    transsplit6_kernel<<<dim3(8, 8, 6), blk, 0, stream>>>(
        wk_ma, wk_ca, wv, wq_ma, wq_ca, wo,
        WTkh, WTkl, WTqh, WTql, WToh, WTol);

    // 2) fused projections (128^2 MFMA tiles)
    proj128_kernel<<<dim3(B_ * KLEN / 128, 1536 / 128), blk, 0, stream>>>(
        keyh, keyl, DIM, WTkh, WTkl, DIM, KPh, KPl, 1536, DIM, bk_ma, bk_ca, bv);
    proj128_kernel<<<dim3(B_ * QLEN / 128, 1024 / 128), blk, 0, stream>>>(
        qh, ql, DIM, WTqh, WTql, DIM, QPh, QPl, 1024, DIM, bq_ma, bq_ca, bq_ca);

    // 3) energies (128^2 MFMA tiles)
    energy128_kernel<<<dim3(QLEN / 128, KLEN / 128, B_ * H_MA), blk, 0, stream>>>(
        QPh, QPl, 1024, 0, KPh, KPl, 1536, 0, PCP, H_MA, 128, r);
    energy128_kernel<<<dim3(QLEN / 128, KLEN / 128, B_ * H_CA), blk, 0, stream>>>(
        QPh, QPl, 1024, 512, KPh, KPl, 1536, 512, SE, H_CA, 256, nullptr);

    // 4) row transforms (DEN holds reciprocal denom)
    ma_row_kernel<<<dim3(B_ * H_MA * QLEN), blk, 0, stream>>>(PCP, ICP);
    ca_row_kernel<<<dim3(B_ * H_CA * QLEN), blk, 0, stream>>>(SE, DEN);

    // 5) monotonic alignment recurrence (round-15 4-wave, verified 131us)
    alpha_kernel<<<dim3(B_ * H_MA), blk, 0, stream>>>(PCP, ICP, PCP);

    // 6) fused beta+cv (CV emitted as bf16 pair; overlays dead key splits)
    fused_cv_kernel<<<dim3(QLEN / 64, B_ * H_MA * H_CA), blk, 0, stream>>>(
        PCP, SE, DEN, KPh, KPl, 1536, CVh, CVl);

    // 7) output projection (64^2 MFMA, 256 blocks)
    mfma_nt_f32_kernel<<<dim3(B_ * QLEN / 64, DIM / 64), blk, 0, stream>>>(
        CVh, CVl, DIM, WToh, WTol, DIM, out, DIM, DIM, bo);
}

// Round 18
// 328.595 us; speedup vs baseline: 1.3006x; 1.0996x over previous
//
#include <hip/hip_runtime.h>
#include <hip/hip_bf16.h>
#include <math.h>

#define DEV_INLINE __device__ __forceinline__

typedef float f32x4 __attribute__((ext_vector_type(4)));
typedef short bf16x8 __attribute__((ext_vector_type(8)));
typedef short s16x4 __attribute__((ext_vector_type(4)));

constexpr int B_    = 4;
constexpr int QLEN  = 512;
constexpr int KLEN  = 1024;
constexpr int DIM   = 512;
constexpr int H_MA  = 4;
constexpr int H_CA  = 2;
constexpr int CHUNK = 4;
constexpr float EPS = 1e-6f;
constexpr float INV_SCALE = 1.0f / 22.62741699796952f;  // 1/sqrt(512)

// ---------------------------------------------------------------------------
// fp32 -> bf16 hi/lo split (RNE both halves; a ~= hi + lo)
// ---------------------------------------------------------------------------

DEV_INLINE unsigned short f2bf(float x) {
    unsigned int u = __float_as_uint(x);
    unsigned int r = u + 0x7FFFu + ((u >> 16) & 1u);
    return (unsigned short)(r >> 16);
}

DEV_INLINE void split2(float x, short& h, short& l) {
    const unsigned short hb = f2bf(x);
    const float hf = __uint_as_float(((unsigned int)hb) << 16);
    h = (short)hb;
    l = (short)f2bf(x - hf);
}

DEV_INLINE float bf2f(short s) {
    return __uint_as_float(((unsigned int)(unsigned short)s) << 16);
}

// key + query split in one launch (index-range decode)
__global__ __launch_bounds__(256) void rowsplit2_kernel(
    const float* __restrict__ X0, short* __restrict__ H0, short* __restrict__ L0, int n0_4,
    const float* __restrict__ X1, short* __restrict__ H1, short* __restrict__ L1, int n1_4)
{
    int i = blockIdx.x * 256 + threadIdx.x;
    const float* X; short* Xh; short* Xl;
    if (i < n0_4) { X = X0; Xh = H0; Xl = L0; }
    else {
        i -= n0_4;
        if (i >= n1_4) return;
        X = X1; Xh = H1; Xl = L1;
    }
    const f32x4 v = *(const f32x4*)(X + (size_t)i * 4);
    s16x4 h, l;
#pragma unroll
    for (int j = 0; j < 4; ++j) {
        short hh, ll;
        split2(v[j], hh, ll);
        h[j] = hh; l[j] = ll;
    }
    *(s16x4*)(Xh + (size_t)i * 4) = h;
    *(s16x4*)(Xl + (size_t)i * 4) = l;
}

// 6 weight matrices fp32[512,512] -> transposed bf16 pairs, one launch
__global__ __launch_bounds__(256) void transsplit6_kernel(
    const float* __restrict__ w0, const float* __restrict__ w1,
    const float* __restrict__ w2, const float* __restrict__ w3,
    const float* __restrict__ w4, const float* __restrict__ w5,
    short* __restrict__ WTkh, short* __restrict__ WTkl,
    short* __restrict__ WTqh, short* __restrict__ WTql,
    short* __restrict__ WToh, short* __restrict__ WTol)
{
    const float* W; short* Dh; short* Dl;
    const int zz = blockIdx.z;
    const int MS = 512 * 512;
    switch (zz) {
        case 0: W = w0; Dh = WTkh;          Dl = WTkl;          break;
        case 1: W = w1; Dh = WTkh + MS;     Dl = WTkl + MS;     break;
        case 2: W = w2; Dh = WTkh + 2 * MS; Dl = WTkl + 2 * MS; break;
        case 3: W = w3; Dh = WTqh;          Dl = WTql;          break;
        case 4: W = w4; Dh = WTqh + MS;     Dl = WTql + MS;     break;
        default: W = w5; Dh = WToh;         Dl = WTol;          break;
    }

    __shared__ __align__(16) short Th[64][72];
    __shared__ __align__(16) short Tl[64][72];
    const int t = threadIdx.x;
    const int k0 = blockIdx.x * 64;
    const int n0 = blockIdx.y * 64;
#pragma unroll
    for (int i = 0; i < 4; ++i) {
        const int c  = t + 256 * i;
        const int kr = c >> 4;
        const int nc = c & 15;
        const f32x4 v = *(const f32x4*)(W + (size_t)(k0 + kr) * DIM + n0 + nc * 4);
#pragma unroll
        for (int j = 0; j < 4; ++j) {
            short h, l;
            split2(v[j], h, l);
            Th[nc * 4 + j][kr] = h;
            Tl[nc * 4 + j][kr] = l;
        }
    }
    __syncthreads();
#pragma unroll
    for (int i = 0; i < 4; ++i) {
        const int c  = t + 256 * i;
        const int nr = c >> 4;
        const int kc = c & 15;
        *(s16x4*)(Dh + (size_t)(n0 + nr) * DIM + k0 + kc * 4) = *(const s16x4*)&Th[nr][kc * 4];
        *(s16x4*)(Dl + (size_t)(n0 + nr) * DIM + k0 + kc * 4) = *(const s16x4*)&Tl[nr][kc * 4];
    }
}

// ---------------------------------------------------------------------------
// 128x128 split-bf16 MFMA NT core
// ---------------------------------------------------------------------------

DEV_INLINE void mfma128_nt_core(
    const short* __restrict__ Ah, const short* __restrict__ Al, int lda,
    const short* __restrict__ Bh, const short* __restrict__ Bl, int ldb,
    int K, int bm, int bn, f32x4 (&acc)[4][4])
{
    __shared__ __align__(16) short AsH[8][4][16][8];
    __shared__ __align__(16) short AsL[8][4][16][8];
    __shared__ __align__(16) short BsH[8][4][16][8];
    __shared__ __align__(16) short BsL[8][4][16][8];
    const int tid  = threadIdx.x;
    const int lane = tid & 63;
    const int w    = tid >> 6;
    const int wm   = w >> 1, wn = w & 1;
    const int lkg  = lane >> 4, lrow = lane & 15;

    for (int k0 = 0; k0 < K; k0 += 32) {
        bf16x8 vah[2], val[2], vbh[2], vbl[2];
#pragma unroll
        for (int p = 0; p < 2; ++p) {
            const int c = p * 256 + tid;
            const int row = c >> 2, kk = c & 3;
            const size_t ao = (size_t)(bm + row) * lda + k0 + kk * 8;
            const size_t bo = (size_t)(bn + row) * ldb + k0 + kk * 8;
            vah[p] = *(const bf16x8*)(Ah + ao);
            val[p] = *(const bf16x8*)(Al + ao);
            vbh[p] = *(const bf16x8*)(Bh + bo);
            vbl[p] = *(const bf16x8*)(Bl + bo);
        }
        __syncthreads();
#pragma unroll
        for (int p = 0; p < 2; ++p) {
            const int c = p * 256 + tid;
            const int row = c >> 2, kk = c & 3;
            const int fm = row >> 4, rr = row & 15;
            *(bf16x8*)&AsH[fm][kk][rr][0] = vah[p];
            *(bf16x8*)&AsL[fm][kk][rr][0] = val[p];
            *(bf16x8*)&BsH[fm][kk][rr][0] = vbh[p];
            *(bf16x8*)&BsL[fm][kk][rr][0] = vbl[p];
        }
        __syncthreads();

        bf16x8 bhf[4], blf[4];
#pragma unroll
        for (int fn = 0; fn < 4; ++fn) {
            bhf[fn] = *(const bf16x8*)&BsH[wn * 4 + fn][lkg][lrow][0];
            blf[fn] = *(const bf16x8*)&BsL[wn * 4 + fn][lkg][lrow][0];
        }
#pragma unroll
        for (int fm = 0; fm < 4; ++fm) {
            const bf16x8 ah = *(const bf16x8*)&AsH[wm * 4 + fm][lkg][lrow][0];
            const bf16x8 al = *(const bf16x8*)&AsL[wm * 4 + fm][lkg][lrow][0];
#pragma unroll
            for (int fn = 0; fn < 4; ++fn) {
                acc[fm][fn] = __builtin_amdgcn_mfma_f32_16x16x32_bf16(ah, bhf[fn], acc[fm][fn], 0, 0, 0);
                acc[fm][fn] = __builtin_amdgcn_mfma_f32_16x16x32_bf16(ah, blf[fn], acc[fm][fn], 0, 0, 0);
                acc[fm][fn] = __builtin_amdgcn_mfma_f32_16x16x32_bf16(al, bhf[fn], acc[fm][fn], 0, 0, 0);
            }
        }
    }
}

// both projections in one launch: blocks 0..383 = key-side (N=1536),
// blocks 384..511 = query-side (N=1024)
__global__ __launch_bounds__(256) void proj_both_kernel(
    const short* __restrict__ Kh, const short* __restrict__ Kl,
    const short* __restrict__ Qh, const short* __restrict__ Ql,
    const short* __restrict__ WTkh, const short* __restrict__ WTkl,
    const short* __restrict__ WTqh, const short* __restrict__ WTql,
    short* __restrict__ KPh, short* __restrict__ KPl,
    short* __restrict__ QPh, short* __restrict__ QPl,
    const float* __restrict__ bkma, const float* __restrict__ bkca,
    const float* __restrict__ bvv_,
    const float* __restrict__ bqma, const float* __restrict__ bqca)
{
    const int bid = blockIdx.x;
    const short *Ah, *Al, *Bh, *Bl;
    short *Ch, *Cl;
    const float *b0, *b1, *b2;
    int bm, bn, ldc;
    if (bid < 384) {
        bm = (bid & 31) * 128; bn = (bid >> 5) * 128;
        Ah = Kh; Al = Kl; Bh = WTkh; Bl = WTkl;
        Ch = KPh; Cl = KPl; ldc = 1536;
        b0 = bkma; b1 = bkca; b2 = bvv_;
    } else {
        const int r = bid - 384;
        bm = (r & 15) * 128; bn = (r >> 4) * 128;
        Ah = Qh; Al = Ql; Bh = WTqh; Bl = WTql;
        Ch = QPh; Cl = QPl; ldc = 1024;
        b0 = bqma; b1 = bqca; b2 = bqca;
    }

    f32x4 acc[4][4] = {};
    mfma128_nt_core(Ah, Al, DIM, Bh, Bl, DIM, DIM, bm, bn, acc);
    const int lane = threadIdx.x & 63;
    const int w = threadIdx.x >> 6;
    const int wm = w >> 1, wn = w & 1;
#pragma unroll
    for (int fm = 0; fm < 4; ++fm)
#pragma unroll
        for (int fn = 0; fn < 4; ++fn) {
            const int col = bn + wn * 64 + fn * 16 + (lane & 15);
            const int seg = col >> 9, cs = col & 511;
            const float bvv = seg == 0 ? b0[cs] : (seg == 1 ? b1[cs] : b2[cs]);
#pragma unroll
            for (int j = 0; j < 4; ++j) {
                const int row = bm + wm * 64 + fm * 16 + (lane >> 4) * 4 + j;
                short h, l;
                split2(acc[fm][fn][j] + bvv, h, l);
                Ch[(size_t)row * ldc + col] = h;
                Cl[(size_t)row * ldc + col] = l;
            }
        }
}

// both energies in one launch: z 0..15 = MA heads, z 16..23 = CA heads
__global__ __launch_bounds__(256) void energy_both_kernel(
    const short* __restrict__ QPh, const short* __restrict__ QPl,
    const short* __restrict__ KPh, const short* __restrict__ KPl,
    float* __restrict__ EMA, float* __restrict__ ECA,
    const float* __restrict__ radd)
{
    const int gz = blockIdx.z;
    int colA0, colB0, HD;
    float* E;
    float addv;
    int b, h;
    if (gz < 16) {
        b = gz >> 2; h = gz & 3;
        colA0 = 0; colB0 = 0; HD = 128;
        E = EMA + (size_t)gz * QLEN * KLEN;
        addv = radd[0];
    } else {
        const int z = gz - 16;
        b = z >> 1; h = z & 1;
        colA0 = 512; colB0 = 512; HD = 256;
        E = ECA + (size_t)z * QLEN * KLEN;
        addv = 0.0f;
    }
    const short* Ah = QPh + (size_t)b * QLEN * 1024 + colA0 + h * HD;
    const short* Al = QPl + (size_t)b * QLEN * 1024 + colA0 + h * HD;
    const short* Bh = KPh + (size_t)b * KLEN * 1536 + colB0 + h * HD;
    const short* Bl = KPl + (size_t)b * KLEN * 1536 + colB0 + h * HD;

    f32x4 acc[4][4] = {};
    const int bm = blockIdx.x * 128, bn = blockIdx.y * 128;
    mfma128_nt_core(Ah, Al, 1024, Bh, Bl, 1536, HD, bm, bn, acc);
    const int lane = threadIdx.x & 63;
    const int w = threadIdx.x >> 6;
    const int wm = w >> 1, wn = w & 1;
#pragma unroll
    for (int fm = 0; fm < 4; ++fm)
#pragma unroll
        for (int fn = 0; fn < 4; ++fn) {
            const int col = bn + wn * 64 + fn * 16 + (lane & 15);
#pragma unroll
            for (int j = 0; j < 4; ++j) {
                const int row = bm + wm * 64 + fm * 16 + (lane >> 4) * 4 + j;
                E[(size_t)row * KLEN + col] = acc[fm][fn][j] * INV_SCALE + addv;
            }
        }
}

// ---------------------------------------------------------------------------
// 64x64 split-bf16 MFMA NT core (round-12 verified) — out-proj
// ---------------------------------------------------------------------------

DEV_INLINE void mfma_nt_core(const short* __restrict__ Ah, const short* __restrict__ Al, int lda,
                             const short* __restrict__ Bh, const short* __restrict__ Bl, int ldb,
                             int K, int bm, int bn, f32x4 (&acc)[2][2])
{
    __shared__ __align__(16) short AsH[4][4][16][8];
    __shared__ __align__(16) short AsL[4][4][16][8];
    __shared__ __align__(16) short BsH[4][4][16][8];
    __shared__ __align__(16) short BsL[4][4][16][8];
    const int tid  = threadIdx.x;
    const int lane = tid & 63;
    const int w    = tid >> 6;
    const int wm   = w >> 1, wn = w & 1;
    const int r    = tid >> 2;
    const int kg   = tid & 3;
    const int rb   = r >> 4, rr = r & 15;
    const int lkg  = lane >> 4, lrr = lane & 15;

    for (int k0 = 0; k0 < K; k0 += 32) {
        const bf16x8 avh = *(const bf16x8*)(Ah + (size_t)(bm + r) * lda + k0 + kg * 8);
        const bf16x8 avl = *(const bf16x8*)(Al + (size_t)(bm + r) * lda + k0 + kg * 8);
        const bf16x8 bvh = *(const bf16x8*)(Bh + (size_t)(bn + r) * ldb + k0 + kg * 8);
        const bf16x8 bvl = *(const bf16x8*)(Bl + (size_t)(bn + r) * ldb + k0 + kg * 8);
        __syncthreads();
        *(bf16x8*)&AsH[rb][kg][rr][0] = avh;
        *(bf16x8*)&AsL[rb][kg][rr][0] = avl;
        *(bf16x8*)&BsH[rb][kg][rr][0] = bvh;
        *(bf16x8*)&BsL[rb][kg][rr][0] = bvl;
        __syncthreads();
#pragma unroll
        for (int fm = 0; fm < 2; ++fm) {
            const bf16x8 ah = *(const bf16x8*)&AsH[wm * 2 + fm][lkg][lrr][0];
            const bf16x8 al = *(const bf16x8*)&AsL[wm * 2 + fm][lkg][lrr][0];
#pragma unroll
            for (int fn = 0; fn < 2; ++fn) {
                const bf16x8 bh = *(const bf16x8*)&BsH[wn * 2 + fn][lkg][lrr][0];
                const bf16x8 bl = *(const bf16x8*)&BsL[wn * 2 + fn][lkg][lrr][0];
                acc[fm][fn] = __builtin_amdgcn_mfma_f32_16x16x32_bf16(ah, bh, acc[fm][fn], 0, 0, 0);
                acc[fm][fn] = __builtin_amdgcn_mfma_f32_16x16x32_bf16(ah, bl, acc[fm][fn], 0, 0, 0);
                acc[fm][fn] = __builtin_amdgcn_mfma_f32_16x16x32_bf16(al, bh, acc[fm][fn], 0, 0, 0);
            }
        }
    }
}

__global__ __launch_bounds__(256) void mfma_nt_f32_kernel(
    const short* __restrict__ Ah, const short* __restrict__ Al, int lda,
    const short* __restrict__ Bh, const short* __restrict__ Bl, int ldb,
    float* __restrict__ C, int ldc, int K,
    const float* __restrict__ bias)
{
    f32x4 acc[2][2] = {};
    const int bm = blockIdx.x * 64, bn = blockIdx.y * 64;
    mfma_nt_core(Ah, Al, lda, Bh, Bl, ldb, K, bm, bn, acc);
    const int lane = threadIdx.x & 63;
    const int w = threadIdx.x >> 6;
    const int wm = w >> 1, wn = w & 1;
#pragma unroll
    for (int fm = 0; fm < 2; ++fm)
#pragma unroll
        for (int fn = 0; fn < 2; ++fn) {
            const int col = bn + wn * 32 + fn * 16 + (lane & 15);
            const float bvv = bias ? bias[col] : 0.0f;
#pragma unroll
            for (int j = 0; j < 4; ++j) {
                const int row = bm + wm * 32 + fm * 16 + (lane >> 4) * 4 + j;
                C[(size_t)row * ldc + col] = acc[fm][fn][j] + bvv;
            }
        }
}

// ---------------------------------------------------------------------------
// merged row transforms: blocks 0..8191 = ma rows, 8192..12287 = ca rows.
// ca stores RDEN = 1/moving_sum.
// ---------------------------------------------------------------------------

__global__ __launch_bounds__(256) void rows_kernel(
    float* __restrict__ PCP, float* __restrict__ ICP,
    float* __restrict__ SE, float* __restrict__ RDEN)
{
    const int bid = blockIdx.x;
    const int tid = threadIdx.x;
    const int lane = tid & 63, wid = tid >> 6;

    if (bid < B_ * H_MA * QLEN) {
        const size_t row = bid;
        float* pe = PCP + row * KLEN;
        float* pi = ICP + row * KLEN;

        const float4 ev = *(const float4*)(pe + tid * 4);
        float e[4] = {ev.x, ev.y, ev.z, ev.w};
        float p[4], l[4], s[4];
        float run = 0.0f;
#pragma unroll
        for (int j = 0; j < 4; ++j) {
            p[j] = 1.0f / (1.0f + expf(-e[j]));
            float om = 1.0f - p[j];
            om = fminf(fmaxf(om, EPS), 1.0f);
            l[j] = logf(om);
            run += l[j];
            s[j] = run;
        }
        const float t = run;
        float v = t;
#pragma unroll
        for (int off = 1; off < 64; off <<= 1) {
            const float u = __shfl_up(v, off);
            if (lane >= off) v += u;
        }
        __shared__ float wsum[4];
        if (lane == 63) wsum[wid] = v;
        __syncthreads();
        float base = v - t;
        for (int w = 0; w < wid; ++w) base += wsum[w];

        float4 po, io;
        float* pp = (float*)&po;
        float* ip = (float*)&io;
#pragma unroll
        for (int j = 0; j < 4; ++j) {
            const float cum = base + s[j];
            const float cp  = expf(cum - l[j]);
            pp[j] = p[j] * cp;
            ip[j] = 1.0f / fmaxf(cp, EPS);
        }
        *(float4*)(pe + tid * 4) = po;
        *(float4*)(pi + tid * 4) = io;
    } else {
        const size_t row = bid - B_ * H_MA * QLEN;
        float* ps = SE + row * KLEN;
        float* pd = RDEN + row * KLEN;

        const float4 ev = *(const float4*)(ps + tid * 4);
        float e[4] = {ev.x, ev.y, ev.z, ev.w};
        float m = fmaxf(fmaxf(e[0], e[1]), fmaxf(e[2], e[3]));
#pragma unroll
        for (int off = 32; off >= 1; off >>= 1)
            m = fmaxf(m, __shfl_xor(m, off));
        __shared__ float wmax[4];
        if (lane == 0) wmax[wid] = m;
        __syncthreads();
        m = fmaxf(fmaxf(wmax[0], wmax[1]), fmaxf(wmax[2], wmax[3]));

        __shared__ float sh[KLEN + 3];
        if (tid < 3) sh[tid] = 0.0f;
        float se[4];
#pragma unroll
        for (int j = 0; j < 4; ++j) {
            se[j] = fmaxf(expf(e[j] - m), 1e-5f);
            sh[3 + tid * 4 + j] = se[j];
        }
        __syncthreads();
        float4 so, do_;
        float* sp = (float*)&so;
        float* dp = (float*)&do_;
#pragma unroll
        for (int j = 0; j < 4; ++j) {
            const int k = tid * 4 + j;
            sp[j] = se[j];
            dp[j] = 1.0f / (sh[3 + k] + sh[2 + k] + sh[1 + k] + sh[k]);
        }
        *(float4*)(ps + tid * 4) = so;
        *(float4*)(pd + tid * 4) = do_;
    }
}

// ---------------------------------------------------------------------------
// alpha recurrence — ROUND-15 4-WAVE VERSION (verified, ~131 us), unchanged.
// ---------------------------------------------------------------------------

template<int CTRL, int ROW_MASK>
DEV_INLINE float dpp_add(float x) {
    int t = __builtin_amdgcn_update_dpp(0, __float_as_int(x), CTRL, ROW_MASK, 0xf, true);
    return x + __int_as_float(t);
}

DEV_INLINE float wave64_incl_scan(float x) {
    x = dpp_add<0x111, 0xf>(x);
    x = dpp_add<0x112, 0xf>(x);
    x = dpp_add<0x114, 0xf>(x);
    x = dpp_add<0x118, 0xf>(x);
    x = dpp_add<0x142, 0xa>(x);
    x = dpp_add<0x143, 0xc>(x);
    return x;
}

typedef __attribute__((address_space(3))) void lv_t;
typedef __attribute__((address_space(1))) const void gv_t;

DEV_INLINE void dma16(const float* g, float* l) {
    __builtin_amdgcn_global_load_lds((gv_t*)g, (lv_t*)l, 16, 0, 0);
}

template<int N> DEV_INLINE void vwait() {
    asm volatile("s_waitcnt vmcnt(%0)" :: "i"(N) : "memory");
    __builtin_amdgcn_sched_barrier(0);
}

template<int N> DEV_INLINE void lwait() {
    asm volatile("s_waitcnt lgkmcnt(%0)" :: "i"(N));
    __builtin_amdgcn_sched_barrier(0);
}

DEV_INLINE void ldsr4(f32x4& d, const float* a_) {
    const unsigned off = (unsigned)(size_t)(lv_t*)a_;
    asm volatile("ds_read_b128 %0, %1" : "=v"(d) : "v"(off));
}

DEV_INLINE void dswr1(float* a_, float v) {
    const unsigned off = (unsigned)(size_t)(lv_t*)a_;
    asm volatile("ds_write_b32 %0, %1" :: "v"(off), "v"(v));
}

DEV_INLINE void sbar() {
    asm volatile("s_barrier" ::: "memory");
}

#define ASTEP(WAITN, BUF, NBUF, PAR, DO_READ, DO_DMA, CG, NG)         \
    {                                                                 \
        vwait<WAITN>();                                               \
        if (DO_READ) {                                                \
            ldsr4(p##NG, &ring[NBUF][0][qoff]);                       \
            ldsr4(i##NG, &ring[NBUF][1][qoff]);                       \
        }                                                             \
        const float t0 = a0 * i##CG[0];                               \
        const float t1 = a1 * i##CG[1];                               \
        const float t2 = a2 * i##CG[2];                               \
        const float t3 = a3 * i##CG[3];                               \
        const float s1 = t0 + t1;                                     \
        const float s2 = s1 + t2;                                     \
        const float s3 = s2 + t3;                                     \
        const float incl = wave64_incl_scan(s3);                      \
        const float excl = incl - s3;                                 \
        if (lane == 63) dswr1(&tot[PAR][wq], incl);                   \
        lwait<0>();                                                   \
        sbar();                                                       \
        f32x4 T;                                                      \
        ldsr4(T, &tot[PAR][0]);                                       \
        lwait<0>();                                                   \
        float Tpre = excl;                                            \
        if (wq > 0) Tpre += T[0];                                     \
        if (wq > 1) Tpre += T[1];                                     \
        if (wq > 2) Tpre += T[2];                                     \
        a0 = p##CG[0] * (Tpre + t0);                                  \
        a1 = p##CG[1] * (Tpre + s1);                                  \
        a2 = p##CG[2] * (Tpre + s2);                                  \
        a3 = p##CG[3] * (Tpre + s3);                                  \
        f32x4 av = {a0, a1, a2, a3};                                  \
        *(f32x4*)st = av;                                             \
        st += KLEN;                                                   \
        __builtin_amdgcn_sched_barrier(0);                            \
        if (DO_DMA) {                                                 \
            dma16(np, &ring[BUF][0][wq * 256]);                       \
            dma16(ni, &ring[BUF][1][wq * 256]);                       \
            np += KLEN; ni += KLEN;                                   \
        }                                                             \
    }

__global__ __launch_bounds__(256) void alpha_kernel(
    const float* __restrict__ PCPin, const float* __restrict__ ICP,
    float* __restrict__ AOUT)
{
    __shared__ __align__(16) float ring[8][2][1024];   // 64 KB
    __shared__ __align__(16) float tot[2][4];          // ping-pong wave totals

    const int z = blockIdx.x;
    const float* base = PCPin + (size_t)z * QLEN * KLEN;
    const float* ibase = ICP + (size_t)z * QLEN * KLEN;
    float* obase = AOUT + (size_t)z * QLEN * KLEN;
    const int tid  = threadIdx.x;
    const int lane = tid & 63;
    const int wq   = tid >> 6;
    const int qoff = wq * 256 + lane * 4;

    {
        const float* pp = base + qoff;
        const float* ip = ibase + qoff;
#pragma unroll
        for (int rr = 0; rr < 8; ++rr) {
            dma16(pp, &ring[rr][0][wq * 256]);
            dma16(ip, &ring[rr][1][wq * 256]);
            pp += KLEN; ip += KLEN;
        }
    }

    f32x4 pA, iA, pB, iB;
    vwait<14>();
    ldsr4(pA, &ring[0][0][qoff]);
    ldsr4(iA, &ring[0][1][qoff]);
    lwait<0>();

    float a0 = 0.0f, a1 = 0.0f, a2 = 0.0f, a3 = 0.0f;
    if (qoff == 0) a0 = 1.0f;

    float* st = obase + qoff;
    const float* np = base + (size_t)8 * KLEN + qoff;
    const float* ni = ibase + (size_t)8 * KLEN + qoff;

    for (int it = 0; it < 63; ++it) {
        ASTEP(12, 0, 1, 0, true, true, A, B)
        ASTEP(12, 1, 2, 1, true, true, B, A)
        ASTEP(12, 2, 3, 0, true, true, A, B)
        ASTEP(12, 3, 4, 1, true, true, B, A)
        ASTEP(12, 4, 5, 0, true, true, A, B)
        ASTEP(12, 5, 6, 1, true, true, B, A)
        ASTEP(12, 6, 7, 0, true, true, A, B)
        ASTEP(12, 7, 0, 1, true, true, B, A)
    }

    ASTEP(12, 0, 1, 0, true, false, A, B)
    ASTEP(10, 1, 2, 1, true, false, B, A)
    ASTEP(8,  2, 3, 0, true, false, A, B)
    ASTEP(6,  3, 4, 1, true, false, B, A)
    ASTEP(4,  4, 5, 0, true, false, A, B)
    ASTEP(2,  5, 6, 1, true, false, B, A)
    ASTEP(0,  6, 7, 0, true, false, A, B)
    ASTEP(0,  7, 0, 1, false, false, B, A)
}

// ---------------------------------------------------------------------------
// fused beta+cv: RDEN holds reciprocals (multiply, not divide).
// ---------------------------------------------------------------------------

__global__ __launch_bounds__(256) void fused_cv_kernel(
    const float* __restrict__ ALPHA, const float* __restrict__ SE,
    const float* __restrict__ RDEN,
    const short* __restrict__ VPh, const short* __restrict__ VPl, int ldv,
    short* __restrict__ CVh, short* __restrict__ CVl)
{
    const int z = blockIdx.y;          // b*8 + hma*2 + hca
    const int b = z >> 3;
    const int h = z & 7;
    const int hma = h >> 1;
    const int hca = h & 1;
    const int bm = blockIdx.x * 64;

    const float* a_base  = ALPHA + ((size_t)b * H_MA + hma) * QLEN * KLEN;
    const float* se_base = SE   + ((size_t)b * H_CA + hca) * QLEN * KLEN;
    const float* dn_base = RDEN + ((size_t)b * H_CA + hca) * QLEN * KLEN;
    const short* vh_base = VPh + (size_t)b * KLEN * ldv + 1024 + h * 64;
    const short* vl_base = VPl + (size_t)b * KLEN * ldv + 1024 + h * 64;
    short* Ch = CVh + (size_t)b * QLEN * DIM + h * 64;
    short* Cl = CVl + (size_t)b * QLEN * DIM + h * 64;

    __shared__ float As[16][68];
    __shared__ float Bs[16][68];
    const int tid  = threadIdx.x;
    const int tm   = (tid >> 4) << 2;
    const int tn   = (tid & 15) << 2;
    const int arow = tid >> 2;
    const int acol = (tid & 3) << 2;
    const int brow = tid >> 4;
    const int bcol = (tid & 15) << 2;
    float acc[4][4] = {};

    for (int k0 = 0; k0 < KLEN; k0 += 16) {
        const int ka = k0 + acol;
        const size_t roff = (size_t)(bm + arow) * KLEN;
        const f32x4 sev = *(const f32x4*)(se_base + roff + ka);
        const f32x4 al0 = *(const f32x4*)(a_base + roff + ka);
        const f32x4 dn0 = *(const f32x4*)(dn_base + roff + ka);
        f32x4 al1 = {0.0f, 0.0f, 0.0f, 0.0f};
        f32x4 dn1 = {1.0f, 1.0f, 1.0f, 1.0f};
        if (ka + 4 < KLEN) {
            al1 = *(const f32x4*)(a_base + roff + ka + 4);
            dn1 = *(const f32x4*)(dn_base + roff + ka + 4);
        }
        float ad[7];
#pragma unroll
        for (int j = 0; j < 4; ++j) ad[j] = al0[j] * dn0[j];
#pragma unroll
        for (int j = 0; j < 3; ++j) ad[4 + j] = al1[j] * dn1[j];
        const s16x4 vh4 = *(const s16x4*)(vh_base + (size_t)(k0 + brow) * ldv + bcol);
        const s16x4 vl4 = *(const s16x4*)(vl_base + (size_t)(k0 + brow) * ldv + bcol);
        __syncthreads();
        As[acol + 0][arow] = sev[0] * (ad[0] + ad[1] + ad[2] + ad[3]);
        As[acol + 1][arow] = sev[1] * (ad[1] + ad[2] + ad[3] + ad[4]);
        As[acol + 2][arow] = sev[2] * (ad[2] + ad[3] + ad[4] + ad[5]);
        As[acol + 3][arow] = sev[3] * (ad[3] + ad[4] + ad[5] + ad[6]);
#pragma unroll
        for (int j = 0; j < 4; ++j)
            Bs[brow][bcol + j] = bf2f(vh4[j]) + bf2f(vl4[j]);
        __syncthreads();
#pragma unroll
        for (int kk = 0; kk < 16; ++kk) {
            const float4 av = *(const float4*)&As[kk][tm];
            const float4 bw = *(const float4*)&Bs[kk][tn];
            const float ar[4] = {av.x, av.y, av.z, av.w};
            const float br[4] = {bw.x, bw.y, bw.z, bw.w};
#pragma unroll
            for (int i = 0; i < 4; ++i)
#pragma unroll
                for (int j = 0; j < 4; ++j)
                    acc[i][j] = fmaf(ar[i], br[j], acc[i][j]);
        }
    }
#pragma unroll
    for (int i = 0; i < 4; ++i) {
        s16x4 oh, ol;
#pragma unroll
        for (int j = 0; j < 4; ++j) {
            short hh, ll;
            split2(acc[i][j], hh, ll);
            oh[j] = hh; ol[j] = ll;
        }
        const size_t ro = (size_t)(bm + tm + i) * DIM + tn;
        *(s16x4*)(Ch + ro) = oh;
        *(s16x4*)(Cl + ro) = ol;
    }
}

// ---------------------------------------------------------------------------

extern "C" void kernel_launch(void* const* d_in, const int* in_sizes, int n_in,
                              void* d_out, int out_size, void* d_ws, size_t ws_size,
                              hipStream_t stream)
{
    (void)in_sizes; (void)n_in; (void)out_size; (void)ws_size;
    const float* key_t = (const float*)d_in[0];
    const float* query = (const float*)d_in[1];
    const float* wk_ma = (const float*)d_in[2];
    const float* bk_ma = (const float*)d_in[3];
    const float* wq_ma = (const float*)d_in[4];
    const float* bq_ma = (const float*)d_in[5];
    const float* r     = (const float*)d_in[6];
    const float* wk_ca = (const float*)d_in[7];
    const float* bk_ca = (const float*)d_in[8];
    const float* wq_ca = (const float*)d_in[9];
    const float* bq_ca = (const float*)d_in[10];
    const float* wv    = (const float*)d_in[11];
    const float* bv    = (const float*)d_in[12];
    const float* wo    = (const float*)d_in[13];
    const float* bo    = (const float*)d_in[14];
    float* out = (float*)d_out;

    // ---- workspace layout: 146 MiB total (unchanged)
    char* w8 = (char*)d_ws;
    size_t off = 0;
    auto take = [&](size_t n) { char* p = w8 + off; off += n; return p; };
    float* PCP = (float*)take(32ull << 20);
    float* ICP = (float*)take(32ull << 20);
    float* SE  = (float*)take(16ull << 20);
    float* DEN = (float*)take(16ull << 20);
    char* keyrg = take(8ull << 20);
    short* keyh = (short*)keyrg;
    short* keyl = (short*)(keyrg + (4ull << 20));
    short* CVh  = (short*)keyrg;
    short* CVl  = (short*)(keyrg + (2ull << 20));
    short* qh = (short*)take(2ull << 20);
    short* ql = (short*)take(2ull << 20);
    short* WTkh = (short*)take((size_t)1536 * 512 * 2);
    short* WTkl = (short*)take((size_t)1536 * 512 * 2);
    short* WTqh = (short*)take((size_t)1024 * 512 * 2);
    short* WTql = (short*)take((size_t)1024 * 512 * 2);
    short* WToh = (short*)take((size_t)512 * 512 * 2);
    short* WTol = (short*)take((size_t)512 * 512 * 2);
    short* KPh = (short*)take((size_t)4096 * 1536 * 2);
    short* KPl = (short*)take((size_t)4096 * 1536 * 2);
    short* QPh = (short*)take((size_t)2048 * 1024 * 2);
    short* QPl = (short*)take((size_t)2048 * 1024 * 2);

    const dim3 blk(256);
    const int KEL4 = B_ * KLEN * DIM / 4;   // key f32x4 count
    const int QEL4 = B_ * QLEN * DIM / 4;   // query f32x4 count

    // 1) conversions: key+query split (1 launch) + 6 weights (1 launch)
    rowsplit2_kernel<<<dim3((KEL4 + QEL4 + 255) / 256), blk, 0, stream>>>(
        key_t, keyh, keyl, KEL4, query, qh, ql, QEL4);
    transsplit6_kernel<<<dim3(8, 8, 6), blk, 0, stream>>>(
        wk_ma, wk_ca, wv, wq_ma, wq_ca, wo,
        WTkh, WTkl, WTqh, WTql, WToh, WTol);

    // 2) both projections (1 launch, 512 blocks)
    proj_both_kernel<<<dim3(512), blk, 0, stream>>>(
        keyh, keyl, qh, ql, WTkh, WTkl, WTqh, WTql,
        KPh, KPl, QPh, QPl, bk_ma, bk_ca, bv, bq_ma, bq_ca);

    // 3) both energies (1 launch, z 0..23)
    energy_both_kernel<<<dim3(QLEN / 128, KLEN / 128, 24), blk, 0, stream>>>(
        QPh, QPl, KPh, KPl, PCP, SE, r);

    // 4) merged row transforms (1 launch)
    rows_kernel<<<dim3(B_ * H_MA * QLEN + B_ * H_CA * QLEN), blk, 0, stream>>>(
        PCP, ICP, SE, DEN);

    // 5) monotonic alignment recurrence (round-15 4-wave, verified)
    alpha_kernel<<<dim3(B_ * H_MA), blk, 0, stream>>>(PCP, ICP, PCP);

    // 6) fused beta+cv
    fused_cv_kernel<<<dim3(QLEN / 64, B_ * H_MA * H_CA), blk, 0, stream>>>(
        PCP, SE, DEN, KPh, KPl, 1536, CVh, CVl);

    // 7) output projection (64^2 MFMA, 256 blocks)
    mfma_nt_f32_kernel<<<dim3(B_ * QLEN / 64, DIM / 64), blk, 0, stream>>>(
        CVh, CVl, DIM, WToh, WTol, DIM, out, DIM, DIM, bo);
}

// Round 19
// 296.678 us; speedup vs baseline: 1.4405x; 1.1076x over previous
//
#include <hip/hip_runtime.h>
#include <hip/hip_bf16.h>
#include <math.h>

#define DEV_INLINE __device__ __forceinline__

typedef float f32x4 __attribute__((ext_vector_type(4)));
typedef short bf16x8 __attribute__((ext_vector_type(8)));
typedef short s16x4 __attribute__((ext_vector_type(4)));

constexpr int B_    = 4;
constexpr int QLEN  = 512;
constexpr int KLEN  = 1024;
constexpr int DIM   = 512;
constexpr int H_MA  = 4;
constexpr int H_CA  = 2;
constexpr int CHUNK = 4;
constexpr float EPS = 1e-6f;
constexpr float INV_SCALE = 1.0f / 22.62741699796952f;  // 1/sqrt(512)

// ---------------------------------------------------------------------------
// fp32 -> bf16 hi/lo split (RNE both halves; a ~= hi + lo)
// ---------------------------------------------------------------------------

DEV_INLINE unsigned short f2bf(float x) {
    unsigned int u = __float_as_uint(x);
    unsigned int r = u + 0x7FFFu + ((u >> 16) & 1u);
    return (unsigned short)(r >> 16);
}

DEV_INLINE void split2(float x, short& h, short& l) {
    const unsigned short hb = f2bf(x);
    const float hf = __uint_as_float(((unsigned int)hb) << 16);
    h = (short)hb;
    l = (short)f2bf(x - hf);
}

DEV_INLINE float bf2f(short s) {
    return __uint_as_float(((unsigned int)(unsigned short)s) << 16);
}

// key + query split in one launch (index-range decode)
__global__ __launch_bounds__(256) void rowsplit2_kernel(
    const float* __restrict__ X0, short* __restrict__ H0, short* __restrict__ L0, int n0_4,
    const float* __restrict__ X1, short* __restrict__ H1, short* __restrict__ L1, int n1_4)
{
    int i = blockIdx.x * 256 + threadIdx.x;
    const float* X; short* Xh; short* Xl;
    if (i < n0_4) { X = X0; Xh = H0; Xl = L0; }
    else {
        i -= n0_4;
        if (i >= n1_4) return;
        X = X1; Xh = H1; Xl = L1;
    }
    const f32x4 v = *(const f32x4*)(X + (size_t)i * 4);
    s16x4 h, l;
#pragma unroll
    for (int j = 0; j < 4; ++j) {
        short hh, ll;
        split2(v[j], hh, ll);
        h[j] = hh; l[j] = ll;
    }
    *(s16x4*)(Xh + (size_t)i * 4) = h;
    *(s16x4*)(Xl + (size_t)i * 4) = l;
}

// 6 weight matrices fp32[512,512] -> transposed bf16 pairs, one launch
__global__ __launch_bounds__(256) void transsplit6_kernel(
    const float* __restrict__ w0, const float* __restrict__ w1,
    const float* __restrict__ w2, const float* __restrict__ w3,
    const float* __restrict__ w4, const float* __restrict__ w5,
    short* __restrict__ WTkh, short* __restrict__ WTkl,
    short* __restrict__ WTqh, short* __restrict__ WTql,
    short* __restrict__ WToh, short* __restrict__ WTol)
{
    const float* W; short* Dh; short* Dl;
    const int zz = blockIdx.z;
    const int MS = 512 * 512;
    switch (zz) {
        case 0: W = w0; Dh = WTkh;          Dl = WTkl;          break;
        case 1: W = w1; Dh = WTkh + MS;     Dl = WTkl + MS;     break;
        case 2: W = w2; Dh = WTkh + 2 * MS; Dl = WTkl + 2 * MS; break;
        case 3: W = w3; Dh = WTqh;          Dl = WTql;          break;
        case 4: W = w4; Dh = WTqh + MS;     Dl = WTql + MS;     break;
        default: W = w5; Dh = WToh;         Dl = WTol;          break;
    }

    __shared__ __align__(16) short Th[64][72];
    __shared__ __align__(16) short Tl[64][72];
    const int t = threadIdx.x;
    const int k0 = blockIdx.x * 64;
    const int n0 = blockIdx.y * 64;
#pragma unroll
    for (int i = 0; i < 4; ++i) {
        const int c  = t + 256 * i;
        const int kr = c >> 4;
        const int nc = c & 15;
        const f32x4 v = *(const f32x4*)(W + (size_t)(k0 + kr) * DIM + n0 + nc * 4);
#pragma unroll
        for (int j = 0; j < 4; ++j) {
            short h, l;
            split2(v[j], h, l);
            Th[nc * 4 + j][kr] = h;
            Tl[nc * 4 + j][kr] = l;
        }
    }
    __syncthreads();
#pragma unroll
    for (int i = 0; i < 4; ++i) {
        const int c  = t + 256 * i;
        const int nr = c >> 4;
        const int kc = c & 15;
        *(s16x4*)(Dh + (size_t)(n0 + nr) * DIM + k0 + kc * 4) = *(const s16x4*)&Th[nr][kc * 4];
        *(s16x4*)(Dl + (size_t)(n0 + nr) * DIM + k0 + kc * 4) = *(const s16x4*)&Tl[nr][kc * 4];
    }
}

// ---------------------------------------------------------------------------
// 128x128 split-bf16 MFMA NT core
// ---------------------------------------------------------------------------

DEV_INLINE void mfma128_nt_core(
    const short* __restrict__ Ah, const short* __restrict__ Al, int lda,
    const short* __restrict__ Bh, const short* __restrict__ Bl, int ldb,
    int K, int bm, int bn, f32x4 (&acc)[4][4])
{
    __shared__ __align__(16) short AsH[8][4][16][8];
    __shared__ __align__(16) short AsL[8][4][16][8];
    __shared__ __align__(16) short BsH[8][4][16][8];
    __shared__ __align__(16) short BsL[8][4][16][8];
    const int tid  = threadIdx.x;
    const int lane = tid & 63;
    const int w    = tid >> 6;
    const int wm   = w >> 1, wn = w & 1;
    const int lkg  = lane >> 4, lrow = lane & 15;

    for (int k0 = 0; k0 < K; k0 += 32) {
        bf16x8 vah[2], val[2], vbh[2], vbl[2];
#pragma unroll
        for (int p = 0; p < 2; ++p) {
            const int c = p * 256 + tid;
            const int row = c >> 2, kk = c & 3;
            const size_t ao = (size_t)(bm + row) * lda + k0 + kk * 8;
            const size_t bo = (size_t)(bn + row) * ldb + k0 + kk * 8;
            vah[p] = *(const bf16x8*)(Ah + ao);
            val[p] = *(const bf16x8*)(Al + ao);
            vbh[p] = *(const bf16x8*)(Bh + bo);
            vbl[p] = *(const bf16x8*)(Bl + bo);
        }
        __syncthreads();
#pragma unroll
        for (int p = 0; p < 2; ++p) {
            const int c = p * 256 + tid;
            const int row = c >> 2, kk = c & 3;
            const int fm = row >> 4, rr = row & 15;
            *(bf16x8*)&AsH[fm][kk][rr][0] = vah[p];
            *(bf16x8*)&AsL[fm][kk][rr][0] = val[p];
            *(bf16x8*)&BsH[fm][kk][rr][0] = vbh[p];
            *(bf16x8*)&BsL[fm][kk][rr][0] = vbl[p];
        }
        __syncthreads();

        bf16x8 bhf[4], blf[4];
#pragma unroll
        for (int fn = 0; fn < 4; ++fn) {
            bhf[fn] = *(const bf16x8*)&BsH[wn * 4 + fn][lkg][lrow][0];
            blf[fn] = *(const bf16x8*)&BsL[wn * 4 + fn][lkg][lrow][0];
        }
#pragma unroll
        for (int fm = 0; fm < 4; ++fm) {
            const bf16x8 ah = *(const bf16x8*)&AsH[wm * 4 + fm][lkg][lrow][0];
            const bf16x8 al = *(const bf16x8*)&AsL[wm * 4 + fm][lkg][lrow][0];
#pragma unroll
            for (int fn = 0; fn < 4; ++fn) {
                acc[fm][fn] = __builtin_amdgcn_mfma_f32_16x16x32_bf16(ah, bhf[fn], acc[fm][fn], 0, 0, 0);
                acc[fm][fn] = __builtin_amdgcn_mfma_f32_16x16x32_bf16(ah, blf[fn], acc[fm][fn], 0, 0, 0);
                acc[fm][fn] = __builtin_amdgcn_mfma_f32_16x16x32_bf16(al, bhf[fn], acc[fm][fn], 0, 0, 0);
            }
        }
    }
}

// both projections in one launch: blocks 0..383 = key-side (N=1536),
// blocks 384..511 = query-side (N=1024)
__global__ __launch_bounds__(256) void proj_both_kernel(
    const short* __restrict__ Kh, const short* __restrict__ Kl,
    const short* __restrict__ Qh, const short* __restrict__ Ql,
    const short* __restrict__ WTkh, const short* __restrict__ WTkl,
    const short* __restrict__ WTqh, const short* __restrict__ WTql,
    short* __restrict__ KPh, short* __restrict__ KPl,
    short* __restrict__ QPh, short* __restrict__ QPl,
    const float* __restrict__ bkma, const float* __restrict__ bkca,
    const float* __restrict__ bvv_,
    const float* __restrict__ bqma, const float* __restrict__ bqca)
{
    const int bid = blockIdx.x;
    const short *Ah, *Al, *Bh, *Bl;
    short *Ch, *Cl;
    const float *b0, *b1, *b2;
    int bm, bn, ldc;
    if (bid < 384) {
        bm = (bid & 31) * 128; bn = (bid >> 5) * 128;
        Ah = Kh; Al = Kl; Bh = WTkh; Bl = WTkl;
        Ch = KPh; Cl = KPl; ldc = 1536;
        b0 = bkma; b1 = bkca; b2 = bvv_;
    } else {
        const int r = bid - 384;
        bm = (r & 15) * 128; bn = (r >> 4) * 128;
        Ah = Qh; Al = Ql; Bh = WTqh; Bl = WTql;
        Ch = QPh; Cl = QPl; ldc = 1024;
        b0 = bqma; b1 = bqca; b2 = bqca;
    }

    f32x4 acc[4][4] = {};
    mfma128_nt_core(Ah, Al, DIM, Bh, Bl, DIM, DIM, bm, bn, acc);
    const int lane = threadIdx.x & 63;
    const int w = threadIdx.x >> 6;
    const int wm = w >> 1, wn = w & 1;
#pragma unroll
    for (int fm = 0; fm < 4; ++fm)
#pragma unroll
        for (int fn = 0; fn < 4; ++fn) {
            const int col = bn + wn * 64 + fn * 16 + (lane & 15);
            const int seg = col >> 9, cs = col & 511;
            const float bvv = seg == 0 ? b0[cs] : (seg == 1 ? b1[cs] : b2[cs]);
#pragma unroll
            for (int j = 0; j < 4; ++j) {
                const int row = bm + wm * 64 + fm * 16 + (lane >> 4) * 4 + j;
                short h, l;
                split2(acc[fm][fn][j] + bvv, h, l);
                Ch[(size_t)row * ldc + col] = h;
                Cl[(size_t)row * ldc + col] = l;
            }
        }
}

// both energies in one launch: z 0..15 = MA heads, z 16..23 = CA heads
__global__ __launch_bounds__(256) void energy_both_kernel(
    const short* __restrict__ QPh, const short* __restrict__ QPl,
    const short* __restrict__ KPh, const short* __restrict__ KPl,
    float* __restrict__ EMA, float* __restrict__ ECA,
    const float* __restrict__ radd)
{
    const int gz = blockIdx.z;
    int colA0, colB0, HD;
    float* E;
    float addv;
    int b, h;
    if (gz < 16) {
        b = gz >> 2; h = gz & 3;
        colA0 = 0; colB0 = 0; HD = 128;
        E = EMA + (size_t)gz * QLEN * KLEN;
        addv = radd[0];
    } else {
        const int z = gz - 16;
        b = z >> 1; h = z & 1;
        colA0 = 512; colB0 = 512; HD = 256;
        E = ECA + (size_t)z * QLEN * KLEN;
        addv = 0.0f;
    }
    const short* Ah = QPh + (size_t)b * QLEN * 1024 + colA0 + h * HD;
    const short* Al = QPl + (size_t)b * QLEN * 1024 + colA0 + h * HD;
    const short* Bh = KPh + (size_t)b * KLEN * 1536 + colB0 + h * HD;
    const short* Bl = KPl + (size_t)b * KLEN * 1536 + colB0 + h * HD;

    f32x4 acc[4][4] = {};
    const int bm = blockIdx.x * 128, bn = blockIdx.y * 128;
    mfma128_nt_core(Ah, Al, 1024, Bh, Bl, 1536, HD, bm, bn, acc);
    const int lane = threadIdx.x & 63;
    const int w = threadIdx.x >> 6;
    const int wm = w >> 1, wn = w & 1;
#pragma unroll
    for (int fm = 0; fm < 4; ++fm)
#pragma unroll
        for (int fn = 0; fn < 4; ++fn) {
            const int col = bn + wn * 64 + fn * 16 + (lane & 15);
#pragma unroll
            for (int j = 0; j < 4; ++j) {
                const int row = bm + wm * 64 + fm * 16 + (lane >> 4) * 4 + j;
                E[(size_t)row * KLEN + col] = acc[fm][fn][j] * INV_SCALE + addv;
            }
        }
}

// ---------------------------------------------------------------------------
// 64x64 split-bf16 MFMA NT core (round-12 verified) — out-proj
// ---------------------------------------------------------------------------

DEV_INLINE void mfma_nt_core(const short* __restrict__ Ah, const short* __restrict__ Al, int lda,
                             const short* __restrict__ Bh, const short* __restrict__ Bl, int ldb,
                             int K, int bm, int bn, f32x4 (&acc)[2][2])
{
    __shared__ __align__(16) short AsH[4][4][16][8];
    __shared__ __align__(16) short AsL[4][4][16][8];
    __shared__ __align__(16) short BsH[4][4][16][8];
    __shared__ __align__(16) short BsL[4][4][16][8];
    const int tid  = threadIdx.x;
    const int lane = tid & 63;
    const int w    = tid >> 6;
    const int wm   = w >> 1, wn = w & 1;
    const int r    = tid >> 2;
    const int kg   = tid & 3;
    const int rb   = r >> 4, rr = r & 15;
    const int lkg  = lane >> 4, lrr = lane & 15;

    for (int k0 = 0; k0 < K; k0 += 32) {
        const bf16x8 avh = *(const bf16x8*)(Ah + (size_t)(bm + r) * lda + k0 + kg * 8);
        const bf16x8 avl = *(const bf16x8*)(Al + (size_t)(bm + r) * lda + k0 + kg * 8);
        const bf16x8 bvh = *(const bf16x8*)(Bh + (size_t)(bn + r) * ldb + k0 + kg * 8);
        const bf16x8 bvl = *(const bf16x8*)(Bl + (size_t)(bn + r) * ldb + k0 + kg * 8);
        __syncthreads();
        *(bf16x8*)&AsH[rb][kg][rr][0] = avh;
        *(bf16x8*)&AsL[rb][kg][rr][0] = avl;
        *(bf16x8*)&BsH[rb][kg][rr][0] = bvh;
        *(bf16x8*)&BsL[rb][kg][rr][0] = bvl;
        __syncthreads();
#pragma unroll
        for (int fm = 0; fm < 2; ++fm) {
            const bf16x8 ah = *(const bf16x8*)&AsH[wm * 2 + fm][lkg][lrr][0];
            const bf16x8 al = *(const bf16x8*)&AsL[wm * 2 + fm][lkg][lrr][0];
#pragma unroll
            for (int fn = 0; fn < 2; ++fn) {
                const bf16x8 bh = *(const bf16x8*)&BsH[wn * 2 + fn][lkg][lrr][0];
                const bf16x8 bl = *(const bf16x8*)&BsL[wn * 2 + fn][lkg][lrr][0];
                acc[fm][fn] = __builtin_amdgcn_mfma_f32_16x16x32_bf16(ah, bh, acc[fm][fn], 0, 0, 0);
                acc[fm][fn] = __builtin_amdgcn_mfma_f32_16x16x32_bf16(ah, bl, acc[fm][fn], 0, 0, 0);
                acc[fm][fn] = __builtin_amdgcn_mfma_f32_16x16x32_bf16(al, bh, acc[fm][fn], 0, 0, 0);
            }
        }
    }
}

__global__ __launch_bounds__(256) void mfma_nt_f32_kernel(
    const short* __restrict__ Ah, const short* __restrict__ Al, int lda,
    const short* __restrict__ Bh, const short* __restrict__ Bl, int ldb,
    float* __restrict__ C, int ldc, int K,
    const float* __restrict__ bias)
{
    f32x4 acc[2][2] = {};
    const int bm = blockIdx.x * 64, bn = blockIdx.y * 64;
    mfma_nt_core(Ah, Al, lda, Bh, Bl, ldb, K, bm, bn, acc);
    const int lane = threadIdx.x & 63;
    const int w = threadIdx.x >> 6;
    const int wm = w >> 1, wn = w & 1;
#pragma unroll
    for (int fm = 0; fm < 2; ++fm)
#pragma unroll
        for (int fn = 0; fn < 2; ++fn) {
            const int col = bn + wn * 32 + fn * 16 + (lane & 15);
            const float bvv = bias ? bias[col] : 0.0f;
#pragma unroll
            for (int j = 0; j < 4; ++j) {
                const int row = bm + wm * 32 + fm * 16 + (lane >> 4) * 4 + j;
                C[(size_t)row * ldc + col] = acc[fm][fn][j] + bvv;
            }
        }
}

// ---------------------------------------------------------------------------
// merged row transforms: blocks 0..8191 = ma rows, 8192..12287 = ca rows.
// ca stores RDEN = 1/moving_sum.
// ---------------------------------------------------------------------------

__global__ __launch_bounds__(256) void rows_kernel(
    float* __restrict__ PCP, float* __restrict__ ICP,
    float* __restrict__ SE, float* __restrict__ RDEN)
{
    const int bid = blockIdx.x;
    const int tid = threadIdx.x;
    const int lane = tid & 63, wid = tid >> 6;

    if (bid < B_ * H_MA * QLEN) {
        const size_t row = bid;
        float* pe = PCP + row * KLEN;
        float* pi = ICP + row * KLEN;

        const float4 ev = *(const float4*)(pe + tid * 4);
        float e[4] = {ev.x, ev.y, ev.z, ev.w};
        float p[4], l[4], s[4];
        float run = 0.0f;
#pragma unroll
        for (int j = 0; j < 4; ++j) {
            p[j] = 1.0f / (1.0f + expf(-e[j]));
            float om = 1.0f - p[j];
            om = fminf(fmaxf(om, EPS), 1.0f);
            l[j] = logf(om);
            run += l[j];
            s[j] = run;
        }
        const float t = run;
        float v = t;
#pragma unroll
        for (int off = 1; off < 64; off <<= 1) {
            const float u = __shfl_up(v, off);
            if (lane >= off) v += u;
        }
        __shared__ float wsum[4];
        if (lane == 63) wsum[wid] = v;
        __syncthreads();
        float base = v - t;
        for (int w = 0; w < wid; ++w) base += wsum[w];

        float4 po, io;
        float* pp = (float*)&po;
        float* ip = (float*)&io;
#pragma unroll
        for (int j = 0; j < 4; ++j) {
            const float cum = base + s[j];
            const float cp  = expf(cum - l[j]);
            pp[j] = p[j] * cp;
            ip[j] = 1.0f / fmaxf(cp, EPS);
        }
        *(float4*)(pe + tid * 4) = po;
        *(float4*)(pi + tid * 4) = io;
    } else {
        const size_t row = bid - B_ * H_MA * QLEN;
        float* ps = SE + row * KLEN;
        float* pd = RDEN + row * KLEN;

        const float4 ev = *(const float4*)(ps + tid * 4);
        float e[4] = {ev.x, ev.y, ev.z, ev.w};
        float m = fmaxf(fmaxf(e[0], e[1]), fmaxf(e[2], e[3]));
#pragma unroll
        for (int off = 32; off >= 1; off >>= 1)
            m = fmaxf(m, __shfl_xor(m, off));
        __shared__ float wmax[4];
        if (lane == 0) wmax[wid] = m;
        __syncthreads();
        m = fmaxf(fmaxf(wmax[0], wmax[1]), fmaxf(wmax[2], wmax[3]));

        __shared__ float sh[KLEN + 3];
        if (tid < 3) sh[tid] = 0.0f;
        float se[4];
#pragma unroll
        for (int j = 0; j < 4; ++j) {
            se[j] = fmaxf(expf(e[j] - m), 1e-5f);
            sh[3 + tid * 4 + j] = se[j];
        }
        __syncthreads();
        float4 so, do_;
        float* sp = (float*)&so;
        float* dp = (float*)&do_;
#pragma unroll
        for (int j = 0; j < 4; ++j) {
            const int k = tid * 4 + j;
            sp[j] = se[j];
            dp[j] = 1.0f / (sh[3 + k] + sh[2 + k] + sh[1 + k] + sh[k]);
        }
        *(float4*)(ps + tid * 4) = so;
        *(float4*)(pd + tid * 4) = do_;
    }
}

// ---------------------------------------------------------------------------
// alpha recurrence — ROUND-15 4-WAVE VERSION (verified, ~131 us), unchanged.
// ---------------------------------------------------------------------------

template<int CTRL, int ROW_MASK>
DEV_INLINE float dpp_add(float x) {
    int t = __builtin_amdgcn_update_dpp(0, __float_as_int(x), CTRL, ROW_MASK, 0xf, true);
    return x + __int_as_float(t);
}

DEV_INLINE float wave64_incl_scan(float x) {
    x = dpp_add<0x111, 0xf>(x);
    x = dpp_add<0x112, 0xf>(x);
    x = dpp_add<0x114, 0xf>(x);
    x = dpp_add<0x118, 0xf>(x);
    x = dpp_add<0x142, 0xa>(x);
    x = dpp_add<0x143, 0xc>(x);
    return x;
}

typedef __attribute__((address_space(3))) void lv_t;
typedef __attribute__((address_space(1))) const void gv_t;

DEV_INLINE void dma16(const float* g, float* l) {
    __builtin_amdgcn_global_load_lds((gv_t*)g, (lv_t*)l, 16, 0, 0);
}

template<int N> DEV_INLINE void vwait() {
    asm volatile("s_waitcnt vmcnt(%0)" :: "i"(N) : "memory");
    __builtin_amdgcn_sched_barrier(0);
}

template<int N> DEV_INLINE void lwait() {
    asm volatile("s_waitcnt lgkmcnt(%0)" :: "i"(N));
    __builtin_amdgcn_sched_barrier(0);
}

DEV_INLINE void ldsr4(f32x4& d, const float* a_) {
    const unsigned off = (unsigned)(size_t)(lv_t*)a_;
    asm volatile("ds_read_b128 %0, %1" : "=v"(d) : "v"(off));
}

DEV_INLINE void dswr1(float* a_, float v) {
    const unsigned off = (unsigned)(size_t)(lv_t*)a_;
    asm volatile("ds_write_b32 %0, %1" :: "v"(off), "v"(v));
}

DEV_INLINE void sbar() {
    asm volatile("s_barrier" ::: "memory");
}

#define ASTEP(WAITN, BUF, NBUF, PAR, DO_READ, DO_DMA, CG, NG)         \
    {                                                                 \
        vwait<WAITN>();                                               \
        if (DO_READ) {                                                \
            ldsr4(p##NG, &ring[NBUF][0][qoff]);                       \
            ldsr4(i##NG, &ring[NBUF][1][qoff]);                       \
        }                                                             \
        const float t0 = a0 * i##CG[0];                               \
        const float t1 = a1 * i##CG[1];                               \
        const float t2 = a2 * i##CG[2];                               \
        const float t3 = a3 * i##CG[3];                               \
        const float s1 = t0 + t1;                                     \
        const float s2 = s1 + t2;                                     \
        const float s3 = s2 + t3;                                     \
        const float incl = wave64_incl_scan(s3);                      \
        const float excl = incl - s3;                                 \
        if (lane == 63) dswr1(&tot[PAR][wq], incl);                   \
        lwait<0>();                                                   \
        sbar();                                                       \
        f32x4 T;                                                      \
        ldsr4(T, &tot[PAR][0]);                                       \
        lwait<0>();                                                   \
        float Tpre = excl;                                            \
        if (wq > 0) Tpre += T[0];                                     \
        if (wq > 1) Tpre += T[1];                                     \
        if (wq > 2) Tpre += T[2];                                     \
        a0 = p##CG[0] * (Tpre + t0);                                  \
        a1 = p##CG[1] * (Tpre + s1);                                  \
        a2 = p##CG[2] * (Tpre + s2);                                  \
        a3 = p##CG[3] * (Tpre + s3);                                  \
        f32x4 av = {a0, a1, a2, a3};                                  \
        *(f32x4*)st = av;                                             \
        st += KLEN;                                                   \
        __builtin_amdgcn_sched_barrier(0);                            \
        if (DO_DMA) {                                                 \
            dma16(np, &ring[BUF][0][wq * 256]);                       \
            dma16(ni, &ring[BUF][1][wq * 256]);                       \
            np += KLEN; ni += KLEN;                                   \
        }                                                             \
    }

__global__ __launch_bounds__(256) void alpha_kernel(
    const float* __restrict__ PCPin, const float* __restrict__ ICP,
    float* __restrict__ AOUT)
{
    __shared__ __align__(16) float ring[8][2][1024];   // 64 KB
    __shared__ __align__(16) float tot[2][4];          // ping-pong wave totals

    const int z = blockIdx.x;
    const float* base = PCPin + (size_t)z * QLEN * KLEN;
    const float* ibase = ICP + (size_t)z * QLEN * KLEN;
    float* obase = AOUT + (size_t)z * QLEN * KLEN;
    const int tid  = threadIdx.x;
    const int lane = tid & 63;
    const int wq   = tid >> 6;
    const int qoff = wq * 256 + lane * 4;

    {
        const float* pp = base + qoff;
        const float* ip = ibase + qoff;
#pragma unroll
        for (int rr = 0; rr < 8; ++rr) {
            dma16(pp, &ring[rr][0][wq * 256]);
            dma16(ip, &ring[rr][1][wq * 256]);
            pp += KLEN; ip += KLEN;
        }
    }

    f32x4 pA, iA, pB, iB;
    vwait<14>();
    ldsr4(pA, &ring[0][0][qoff]);
    ldsr4(iA, &ring[0][1][qoff]);
    lwait<0>();

    float a0 = 0.0f, a1 = 0.0f, a2 = 0.0f, a3 = 0.0f;
    if (qoff == 0) a0 = 1.0f;

    float* st = obase + qoff;
    const float* np = base + (size_t)8 * KLEN + qoff;
    const float* ni = ibase + (size_t)8 * KLEN + qoff;

    for (int it = 0; it < 63; ++it) {
        ASTEP(12, 0, 1, 0, true, true, A, B)
        ASTEP(12, 1, 2, 1, true, true, B, A)
        ASTEP(12, 2, 3, 0, true, true, A, B)
        ASTEP(12, 3, 4, 1, true, true, B, A)
        ASTEP(12, 4, 5, 0, true, true, A, B)
        ASTEP(12, 5, 6, 1, true, true, B, A)
        ASTEP(12, 6, 7, 0, true, true, A, B)
        ASTEP(12, 7, 0, 1, true, true, B, A)
    }

    ASTEP(12, 0, 1, 0, true, false, A, B)
    ASTEP(10, 1, 2, 1, true, false, B, A)
    ASTEP(8,  2, 3, 0, true, false, A, B)
    ASTEP(6,  3, 4, 1, true, false, B, A)
    ASTEP(4,  4, 5, 0, true, false, A, B)
    ASTEP(2,  5, 6, 1, true, false, B, A)
    ASTEP(0,  6, 7, 0, true, false, A, B)
    ASTEP(0,  7, 0, 1, false, false, B, A)
}

// ---------------------------------------------------------------------------
// fused beta+cv via split-bf16 MFMA (64x64 tile, verified frag layouts):
// beta computed fp32 in registers -> split2 into A-frag LDS; V (bf16 pair)
// staged transposed into B-frag LDS; 12 MFMA/wave per K=32 tile.
// ---------------------------------------------------------------------------

__global__ __launch_bounds__(256) void fused_cv_mfma_kernel(
    const float* __restrict__ ALPHA, const float* __restrict__ SE,
    const float* __restrict__ RDEN,
    const short* __restrict__ VPh, const short* __restrict__ VPl, int ldv,
    short* __restrict__ CVh, short* __restrict__ CVl)
{
    const int z = blockIdx.y;          // b*8 + hma*2 + hca
    const int b = z >> 3;
    const int h = z & 7;
    const int hma = h >> 1;
    const int hca = h & 1;
    const int bm = blockIdx.x * 64;

    const float* a_base  = ALPHA + ((size_t)b * H_MA + hma) * QLEN * KLEN;
    const float* se_base = SE   + ((size_t)b * H_CA + hca) * QLEN * KLEN;
    const float* dn_base = RDEN + ((size_t)b * H_CA + hca) * QLEN * KLEN;
    const short* vh_base = VPh + (size_t)b * KLEN * ldv + 1024 + h * 64;
    const short* vl_base = VPl + (size_t)b * KLEN * ldv + 1024 + h * 64;
    short* Ch = CVh + (size_t)b * QLEN * DIM + h * 64;
    short* Cl = CVl + (size_t)b * QLEN * DIM + h * 64;

    __shared__ __align__(16) short AsH[4][4][16][8];
    __shared__ __align__(16) short AsL[4][4][16][8];
    __shared__ __align__(16) short BsH[4][4][16][8];
    __shared__ __align__(16) short BsL[4][4][16][8];

    const int tid  = threadIdx.x;
    const int lane = tid & 63;
    const int w    = tid >> 6;
    const int wm   = w >> 1, wn = w & 1;
    const int lkg  = lane >> 4, lrr = lane & 15;
    // beta staging decode: 64 rows x 4 k-octets
    const int arow = tid >> 2;         // 0..63
    const int aoct = tid & 3;          // 0..3 (8 k each)
    // V staging decode: 32 k x 8 n-octets
    const int vk  = tid >> 3;          // 0..31
    const int vn8 = (tid & 7) * 8;     // 0..56

    f32x4 acc[2][2] = {};

    for (int k0 = 0; k0 < KLEN; k0 += 32) {
        // ---- compute 8 beta values (fp32) and split to bf16 pair
        const int ka = k0 + aoct * 8;
        const size_t roff = (size_t)(bm + arow) * KLEN;
        const f32x4 se0 = *(const f32x4*)(se_base + roff + ka);
        const f32x4 se1 = *(const f32x4*)(se_base + roff + ka + 4);
        const f32x4 al0 = *(const f32x4*)(a_base + roff + ka);
        const f32x4 al1 = *(const f32x4*)(a_base + roff + ka + 4);
        const f32x4 dn0 = *(const f32x4*)(dn_base + roff + ka);
        const f32x4 dn1 = *(const f32x4*)(dn_base + roff + ka + 4);
        f32x4 al2 = {0.0f, 0.0f, 0.0f, 0.0f};
        f32x4 dn2 = {1.0f, 1.0f, 1.0f, 1.0f};
        if (ka + 8 < KLEN) {
            al2 = *(const f32x4*)(a_base + roff + ka + 8);
            dn2 = *(const f32x4*)(dn_base + roff + ka + 8);
        }
        float ad[11];
#pragma unroll
        for (int j = 0; j < 4; ++j) ad[j] = al0[j] * dn0[j];
#pragma unroll
        for (int j = 0; j < 4; ++j) ad[4 + j] = al1[j] * dn1[j];
#pragma unroll
        for (int j = 0; j < 3; ++j) ad[8 + j] = al2[j] * dn2[j];
        bf16x8 bh_, bl_;
#pragma unroll
        for (int j = 0; j < 8; ++j) {
            const float sej = j < 4 ? se0[j] : se1[j - 4];
            const float beta = sej * (ad[j] + ad[j + 1] + ad[j + 2] + ad[j + 3]);
            short hh, ll;
            split2(beta, hh, ll);
            bh_[j] = hh; bl_[j] = ll;
        }
        // ---- V loads (row-major bf16 pair)
        const bf16x8 vvh = *(const bf16x8*)(vh_base + (size_t)(k0 + vk) * ldv + vn8);
        const bf16x8 vvl = *(const bf16x8*)(vl_base + (size_t)(k0 + vk) * ldv + vn8);
        __syncthreads();
        // beta -> A frag: A[m=arow][k] ; [fm][kg][m&15][j]
        *(bf16x8*)&AsH[arow >> 4][aoct][arow & 15][0] = bh_;
        *(bf16x8*)&AsL[arow >> 4][aoct][arow & 15][0] = bl_;
        // V -> B frag (transpose): B[n][k=vk] ; [n>>4][vk>>3][n&15][vk&7]
#pragma unroll
        for (int j = 0; j < 8; ++j) {
            const int n = vn8 + j;
            BsH[n >> 4][vk >> 3][n & 15][vk & 7] = vvh[j];
            BsL[n >> 4][vk >> 3][n & 15][vk & 7] = vvl[j];
        }
        __syncthreads();
#pragma unroll
        for (int fm = 0; fm < 2; ++fm) {
            const bf16x8 ah = *(const bf16x8*)&AsH[wm * 2 + fm][lkg][lrr][0];
            const bf16x8 al = *(const bf16x8*)&AsL[wm * 2 + fm][lkg][lrr][0];
#pragma unroll
            for (int fn = 0; fn < 2; ++fn) {
                const bf16x8 vh = *(const bf16x8*)&BsH[wn * 2 + fn][lkg][lrr][0];
                const bf16x8 vl = *(const bf16x8*)&BsL[wn * 2 + fn][lkg][lrr][0];
                acc[fm][fn] = __builtin_amdgcn_mfma_f32_16x16x32_bf16(ah, vh, acc[fm][fn], 0, 0, 0);
                acc[fm][fn] = __builtin_amdgcn_mfma_f32_16x16x32_bf16(ah, vl, acc[fm][fn], 0, 0, 0);
                acc[fm][fn] = __builtin_amdgcn_mfma_f32_16x16x32_bf16(al, vh, acc[fm][fn], 0, 0, 0);
            }
        }
    }

    // epilogue: D[m=(l>>4)*4+j][n=l&15] -> CV bf16 pair
#pragma unroll
    for (int fm = 0; fm < 2; ++fm)
#pragma unroll
        for (int fn = 0; fn < 2; ++fn) {
            const int col = wn * 32 + fn * 16 + (lane & 15);
#pragma unroll
            for (int j = 0; j < 4; ++j) {
                const int row = bm + wm * 32 + fm * 16 + (lane >> 4) * 4 + j;
                short hh, ll;
                split2(acc[fm][fn][j], hh, ll);
                const size_t ro = (size_t)row * DIM + col;
                Ch[ro] = hh;
                Cl[ro] = ll;
            }
        }
}

// ---------------------------------------------------------------------------

extern "C" void kernel_launch(void* const* d_in, const int* in_sizes, int n_in,
                              void* d_out, int out_size, void* d_ws, size_t ws_size,
                              hipStream_t stream)
{
    (void)in_sizes; (void)n_in; (void)out_size; (void)ws_size;
    const float* key_t = (const float*)d_in[0];
    const float* query = (const float*)d_in[1];
    const float* wk_ma = (const float*)d_in[2];
    const float* bk_ma = (const float*)d_in[3];
    const float* wq_ma = (const float*)d_in[4];
    const float* bq_ma = (const float*)d_in[5];
    const float* r     = (const float*)d_in[6];
    const float* wk_ca = (const float*)d_in[7];
    const float* bk_ca = (const float*)d_in[8];
    const float* wq_ca = (const float*)d_in[9];
    const float* bq_ca = (const float*)d_in[10];
    const float* wv    = (const float*)d_in[11];
    const float* bv    = (const float*)d_in[12];
    const float* wo    = (const float*)d_in[13];
    const float* bo    = (const float*)d_in[14];
    float* out = (float*)d_out;

    // ---- workspace layout: 146 MiB total (unchanged)
    char* w8 = (char*)d_ws;
    size_t off = 0;
    auto take = [&](size_t n) { char* p = w8 + off; off += n; return p; };
    float* PCP = (float*)take(32ull << 20);
    float* ICP = (float*)take(32ull << 20);
    float* SE  = (float*)take(16ull << 20);
    float* DEN = (float*)take(16ull << 20);
    char* keyrg = take(8ull << 20);
    short* keyh = (short*)keyrg;
    short* keyl = (short*)(keyrg + (4ull << 20));
    short* CVh  = (short*)keyrg;
    short* CVl  = (short*)(keyrg + (2ull << 20));
    short* qh = (short*)take(2ull << 20);
    short* ql = (short*)take(2ull << 20);
    short* WTkh = (short*)take((size_t)1536 * 512 * 2);
    short* WTkl = (short*)take((size_t)1536 * 512 * 2);
    short* WTqh = (short*)take((size_t)1024 * 512 * 2);
    short* WTql = (short*)take((size_t)1024 * 512 * 2);
    short* WToh = (short*)take((size_t)512 * 512 * 2);
    short* WTol = (short*)take((size_t)512 * 512 * 2);
    short* KPh = (short*)take((size_t)4096 * 1536 * 2);
    short* KPl = (short*)take((size_t)4096 * 1536 * 2);
    short* QPh = (short*)take((size_t)2048 * 1024 * 2);
    short* QPl = (short*)take((size_t)2048 * 1024 * 2);

    const dim3 blk(256);
    const int KEL4 = B_ * KLEN * DIM / 4;
    const int QEL4 = B_ * QLEN * DIM / 4;

    // 1) conversions
    rowsplit2_kernel<<<dim3((KEL4 + QEL4 + 255) / 256), blk, 0, stream>>>(
        key_t, keyh, keyl, KEL4, query, qh, ql, QEL4);
    transsplit6_kernel<<<dim3(8, 8, 6), blk, 0, stream>>>(
        wk_ma, wk_ca, wv, wq_ma, wq_ca, wo,
        WTkh, WTkl, WTqh, WTql, WToh, WTol);

    // 2) both projections (1 launch, 512 blocks)
    proj_both_kernel<<<dim3(512), blk, 0, stream>>>(
        keyh, keyl, qh, ql, WTkh, WTkl, WTqh, WTql,
        KPh, KPl, QPh, QPl, bk_ma, bk_ca, bv, bq_ma, bq_ca);

    // 3) both energies (1 launch)
    energy_both_kernel<<<dim3(QLEN / 128, KLEN / 128, 24), blk, 0, stream>>>(
        QPh, QPl, KPh, KPl, PCP, SE, r);

    // 4) merged row transforms
    rows_kernel<<<dim3(B_ * H_MA * QLEN + B_ * H_CA * QLEN), blk, 0, stream>>>(
        PCP, ICP, SE, DEN);

    // 5) monotonic alignment recurrence (round-15 4-wave, verified)
    alpha_kernel<<<dim3(B_ * H_MA), blk, 0, stream>>>(PCP, ICP, PCP);

    // 6) fused beta+cv via MFMA
    fused_cv_mfma_kernel<<<dim3(QLEN / 64, B_ * H_MA * H_CA), blk, 0, stream>>>(
        PCP, SE, DEN, KPh, KPl, 1536, CVh, CVl);

    // 7) output projection (64^2 MFMA, 256 blocks)
    mfma_nt_f32_kernel<<<dim3(B_ * QLEN / 64, DIM / 64), blk, 0, stream>>>(
        CVh, CVl, DIM, WToh, WTol, DIM, out, DIM, DIM, bo);
}